// Round 6
// baseline (593.856 us; speedup 1.0000x reference)
//
#include <hip/hip_runtime.h>
#include <hip/hip_bf16.h>
#include <limits.h>

// ---------------- problem constants ----------------
#define N_NODES 50000
#define N_EDGES 800000
#define TOT_E   (N_EDGES + N_NODES)   // with self loops
#define IN_F    38
#define HIDC    64
#define NH      4
#define F1      256                    // NH*HIDC
#define F2      128                    // OUT
#define NGRAPH  128
#define NEG_SLOPE 0.2f
#define EPS_A   1e-16f

typedef __hip_bfloat16 bf16;
typedef __attribute__((ext_vector_type(8))) short short8;
typedef __attribute__((ext_vector_type(4))) float f32x4;
typedef __attribute__((ext_vector_type(2))) float f2;   // lowers to VOP3P v_pk_*_f32

// ---------------- ws layout ----------------
constexpr size_t al256(size_t x) { return (x + 255) & ~(size_t)255; }

// converted-params element offsets (f32 elements)
#define P_WL1   0
#define P_BL1   (P_WL1 + IN_F * F1)
#define P_WR1   (P_BL1 + F1)
#define P_BR1   (P_WR1 + IN_F * F1)
#define P_ATT1  (P_BR1 + F1)
#define P_BIAS1 (P_ATT1 + F1)
#define P_WL2   (P_BIAS1 + F1)
#define P_BL2   (P_WL2 + F1 * F2)
#define P_WR2   (P_BL2 + F2)
#define P_BR2   (P_WR2 + F1 * F2)
#define P_ATT2  (P_BR2 + F2)
#define P_BIAS2 (P_ATT2 + F2)
#define P_TOTAL (P_BIAS2 + F2)

constexpr size_t OFF_FLAG = 0;
constexpr size_t OFF_PAR  = 256;
constexpr size_t OFF_XL1  = OFF_PAR + al256((size_t)P_TOTAL * 4);   // reused as h2 later
constexpr size_t OFF_XR1  = OFF_XL1 + al256((size_t)N_NODES * F1 * 2);
constexpr size_t OFF_H    = OFF_XR1 + al256((size_t)N_NODES * F1 * 2);
constexpr size_t OFF_XL2  = OFF_H   + al256((size_t)N_NODES * F1 * 2);
constexpr size_t OFF_XR2  = OFF_XL2 + al256((size_t)N_NODES * F2 * 2);
constexpr size_t OFF_CNT  = OFF_XR2 + al256((size_t)N_NODES * F2 * 2);
constexpr size_t OFF_OFFS = OFF_CNT + al256((size_t)N_NODES * 4);
constexpr size_t OFF_CUR  = OFF_OFFS+ al256((size_t)(N_NODES + 1) * 4);
constexpr size_t OFF_CSR  = OFF_CUR + al256((size_t)(N_NODES + 1) * 4);
constexpr size_t OFF_GS   = OFF_CSR + al256((size_t)TOT_E * 4);
constexpr size_t OFF_GE   = OFF_GS  + al256((size_t)NGRAPH * 4);
constexpr size_t OFF_WT1  = OFF_GE  + al256((size_t)NGRAPH * 4);    // 512x64 bf16
constexpr size_t OFF_WT2  = OFF_WT1 + al256((size_t)512 * 64 * 2);  // 256x256 bf16
constexpr size_t OFF_H2   = OFF_XL1;  // xl1 dead after agg1
constexpr size_t OFF_XB   = OFF_H;    // xb (N x 64 bf16) dead before agg1 writes h

// ---------------- helpers ----------------
// 16B (8 bf16) -> 4 x f2; pairs are (ch 2i, ch 2i+1)
__device__ __forceinline__ void load8bf2(const bf16* __restrict__ p, f2* f) {
  uint4 q = *(const uint4*)p;
  unsigned v[4] = {q.x, q.y, q.z, q.w};
#pragma unroll
  for (int i = 0; i < 4; i++) {
    f2 t;
    t.x = __uint_as_float(v[i] << 16);
    t.y = __uint_as_float(v[i] & 0xffff0000u);
    f[i] = t;
  }
}

// leaky_relu(s) = 0.6*s + 0.4*|s|  (== s for s>0, 0.2s for s<0) -> pk_mul + pk_fma
__device__ __forceinline__ f2 lrelu2(f2 s) {
  f2 as;
  as.x = __uint_as_float(__float_as_uint(s.x) & 0x7fffffffu);
  as.y = __uint_as_float(__float_as_uint(s.y) & 0x7fffffffu);
  return 0.6f * s + 0.4f * as;
}

// ---------------- dtype detection (1 = f32 inputs, 0 = bf16) ----------------
__global__ void detect_k(const void* __restrict__ x, int* __restrict__ flag) {
  const int lane = threadIdx.x;
  const unsigned short* u = (const unsigned short*)x;
  unsigned short b = u[lane];
  int e = (b >> 7) & 0xFF;
  int insane = !((e == 0) || (e >= 96 && e <= 158));
#pragma unroll
  for (int off = 32; off > 0; off >>= 1) insane += __shfl_xor(insane, off, 64);
  if (lane == 0) *flag = (insane > 8) ? 1 : 0;
}

// ---------------- param conversion -> f32 scratch ----------------
struct CvtArgs { const void* src[12]; int n[12]; int dstoff[12]; };

__global__ void convert_k(CvtArgs a, const int* __restrict__ flag,
                          float* __restrict__ dst) {
  const int row = blockIdx.y;
  const int i = blockIdx.x * 256 + threadIdx.x;
  if (i >= a.n[row]) return;
  float v = (*flag) ? ((const float*)a.src[row])[i]
                    : (float)((const bf16*)a.src[row])[i];
  dst[a.dstoff[row] + i] = v;
}

// ---------------- MFMA prep: x -> xb (N x 64 bf16, zero-padded K) ----------------
__global__ void xprep_k(const int* __restrict__ flag, const void* __restrict__ x,
                        bf16* __restrict__ xb) {
  int i = blockIdx.x * 256 + threadIdx.x;       // i = n*64 + k
  if (i >= N_NODES * 64) return;
  int n = i >> 6, k = i & 63;
  float v = 0.f;
  if (k < IN_F) {
    int idx = n * IN_F + k;
    v = (*flag) ? ((const float*)x)[idx] : (float)((const bf16*)x)[idx];
  }
  xb[i] = (bf16)v;
}

// Wt1[n][k]: n in [0,512) (n<256 -> Wl1 col n, else Wr1 col n-256), k in [0,64) zero-padded
__global__ void wprep1_k(const int* __restrict__ flag,
                         const void* __restrict__ Wl, const void* __restrict__ Wr,
                         bf16* __restrict__ wt1) {
  int i = blockIdx.x * 256 + threadIdx.x;       // i = n*64 + k
  if (i >= 512 * 64) return;
  int n = i >> 6, k = i & 63;
  float v = 0.f;
  if (k < IN_F) {
    const void* W = (n < F1) ? Wl : Wr;
    int col = (n < F1) ? n : n - F1;
    int idx = k * F1 + col;
    v = (*flag) ? ((const float*)W)[idx] : (float)((const bf16*)W)[idx];
  }
  wt1[i] = (bf16)v;
}

// Wt2[n][k]: n in [0,256) (n<128 -> Wl2 col n, else Wr2 col n-128), k in [0,256)
__global__ void wprep2_k(const int* __restrict__ flag,
                         const void* __restrict__ Wl, const void* __restrict__ Wr,
                         bf16* __restrict__ wt2) {
  int i = blockIdx.x * 256 + threadIdx.x;       // i = n*256 + k
  if (i >= 256 * 256) return;
  int n = i >> 8, k = i & 255;
  const void* W = (n < F2) ? Wl : Wr;
  int col = (n < F2) ? n : n - F2;
  int idx = k * F2 + col;
  float v = (*flag) ? ((const float*)W)[idx] : (float)((const bf16*)W)[idx];
  wt2[i] = (bf16)v;
}

// ---------------- GEMM 1 (MFMA): xb(N,64) @ Wt1^T -> xl1|xr1 (N,256 each) ----------------
__global__ __launch_bounds__(256) void gemm1_mfma_k(
    const bf16* __restrict__ xb, const bf16* __restrict__ wt1,
    const float* __restrict__ par,
    bf16* __restrict__ xl1, bf16* __restrict__ xr1) {
  const int w = threadIdx.x >> 6, lane = threadIdx.x & 63;
  const int m0 = blockIdx.x * 32 + (w & 1) * 16;
  const int colbase = (w >> 1) * 256;
  const int lm = lane & 15, lk = lane >> 4;

  int arow = m0 + lm; if (arow >= N_NODES) arow = N_NODES - 1;
  const short8 a0 = *(const short8*)(xb + (size_t)arow * 64 + lk * 8);
  const short8 a1 = *(const short8*)(xb + (size_t)arow * 64 + 32 + lk * 8);

  f32x4 acc[16];
  const f32x4 z = {0.f, 0.f, 0.f, 0.f};
#pragma unroll
  for (int nt = 0; nt < 16; nt++) acc[nt] = z;

#pragma unroll
  for (int nt = 0; nt < 16; nt++) {
    int n = colbase + nt * 16 + lm;
    short8 b0 = *(const short8*)(wt1 + (size_t)n * 64 + lk * 8);
    short8 b1 = *(const short8*)(wt1 + (size_t)n * 64 + 32 + lk * 8);
    acc[nt] = __builtin_amdgcn_mfma_f32_16x16x32_bf16(a0, b0, acc[nt], 0, 0, 0);
    acc[nt] = __builtin_amdgcn_mfma_f32_16x16x32_bf16(a1, b1, acc[nt], 0, 0, 0);
  }

  const int r0 = m0 + (lane >> 4) * 4;
#pragma unroll
  for (int nt = 0; nt < 16; nt++) {
    int col = colbase + nt * 16 + lm;
    bf16* dst = (col < F1) ? xl1 : xr1;
    int c = (col < F1) ? col : col - F1;
    float bv = (col < F1) ? par[P_BL1 + c] : par[P_BR1 + c];
#pragma unroll
    for (int reg = 0; reg < 4; reg++) {
      int row = r0 + reg;
      if (row < N_NODES)
        dst[(size_t)row * F1 + c] = (bf16)(acc[nt][reg] + bv);
    }
  }
}

// ---------------- GEMM 2 (MFMA): h(N,256) @ Wt2^T -> xl2|xr2 (N,128 each) ----------------
__global__ __launch_bounds__(256) void gemm2_mfma_k(
    const bf16* __restrict__ h, const bf16* __restrict__ wt2,
    const float* __restrict__ par,
    bf16* __restrict__ xl2, bf16* __restrict__ xr2) {
  const int w = threadIdx.x >> 6, lane = threadIdx.x & 63;
  const int m0 = blockIdx.x * 32 + (w & 1) * 16;
  const int colbase = (w >> 1) * 128;
  const int lm = lane & 15, lk = lane >> 4;

  int arow = m0 + lm; if (arow >= N_NODES) arow = N_NODES - 1;
  const bf16* hrow = h + (size_t)arow * F1 + lk * 8;

  f32x4 acc[8];
  const f32x4 z = {0.f, 0.f, 0.f, 0.f};
#pragma unroll
  for (int nt = 0; nt < 8; nt++) acc[nt] = z;

#pragma unroll
  for (int kk = 0; kk < 256; kk += 32) {
    short8 a = *(const short8*)(hrow + kk);
#pragma unroll
    for (int nt = 0; nt < 8; nt++) {
      int n = colbase + nt * 16 + lm;
      short8 b = *(const short8*)(wt2 + (size_t)n * 256 + kk + lk * 8);
      acc[nt] = __builtin_amdgcn_mfma_f32_16x16x32_bf16(a, b, acc[nt], 0, 0, 0);
    }
  }

  const int r0 = m0 + (lane >> 4) * 4;
#pragma unroll
  for (int nt = 0; nt < 8; nt++) {
    int col = colbase + nt * 16 + lm;
    bf16* dst = (col < F2) ? xl2 : xr2;
    int c = (col < F2) ? col : col - F2;
    float bv = (col < F2) ? par[P_BL2 + c] : par[P_BR2 + c];
#pragma unroll
    for (int reg = 0; reg < 4; reg++) {
      int row = r0 + reg;
      if (row < N_NODES)
        dst[(size_t)row * F2 + c] = (bf16)(acc[nt][reg] + bv);
    }
  }
}

// ---------------- CSR build ----------------
__global__ void count_k(const int* __restrict__ ei, int* __restrict__ cnt) {
  int e = blockIdx.x * 256 + threadIdx.x;
  if (e >= TOT_E) return;
  int dst = (e < N_EDGES) ? ei[N_EDGES + e] : (e - N_EDGES);
  atomicAdd(&cnt[dst], 1);
}

__global__ __launch_bounds__(1024) void scan_k(const int* __restrict__ cnt,
                                               int* __restrict__ offs,
                                               int* __restrict__ cursor) {
  __shared__ int wsum[16];
  __shared__ int carry_s;
  const int t = threadIdx.x;
  const int lane = t & 63, w = t >> 6;
  if (t == 0) carry_s = 0;
  __syncthreads();
  for (int base = 0; base < N_NODES; base += 1024) {
    int idx = base + t;
    int v = (idx < N_NODES) ? cnt[idx] : 0;
    int s = v;
#pragma unroll
    for (int off = 1; off < 64; off <<= 1) {
      int u = __shfl_up(s, off, 64);
      if (lane >= off) s += u;
    }
    if (lane == 63) wsum[w] = s;
    __syncthreads();
    int prefix = carry_s;
    for (int i = 0; i < w; i++) prefix += wsum[i];
    int excl = prefix + s - v;
    if (idx < N_NODES) { offs[idx] = excl; cursor[idx] = excl; }
    __syncthreads();
    if (t == 1023) carry_s = prefix + s;
    __syncthreads();
  }
  if (t == 0) offs[N_NODES] = carry_s;
}

__global__ void scatter_k(const int* __restrict__ ei, int* __restrict__ cursor,
                          int* __restrict__ csr) {
  int e = blockIdx.x * 256 + threadIdx.x;
  if (e >= TOT_E) return;
  int src, dst;
  if (e < N_EDGES) { src = ei[e]; dst = ei[N_EDGES + e]; }
  else             { src = dst = e - N_EDGES; }
  int pos = atomicAdd(&cursor[dst], 1);
  csr[pos] = src;
}

// ---------------- layer-1 aggregation (packed-f32 math) ----------------
// Block = 4 waves, wave = head. Wave: 8 groups x 8 lanes; group g = edge base+g,
// lane sl holds channels chbase..chbase+7 as 4 x f2.
__global__ __launch_bounds__(256, 4) void agg1_k(
    const bf16* __restrict__ xl1, const bf16* __restrict__ xr1,
    const float* __restrict__ par,
    const int* __restrict__ offs, const int* __restrict__ csr,
    bf16* __restrict__ hout) {
  const int dst = blockIdx.x;
  const int t = threadIdx.x;
  const int w = t >> 6;
  const int lane = t & 63;
  const int g = lane >> 3;
  const int sl = lane & 7;
  const int chbase = w * HIDC + sl * 8;

  f2 r2[4], a2[4];
  load8bf2(xr1 + (size_t)dst * F1 + chbase, r2);
  {
    float4 aa = *(const float4*)(par + P_ATT1 + chbase);
    float4 ab = *(const float4*)(par + P_ATT1 + chbase + 4);
    a2[0].x = aa.x; a2[0].y = aa.y; a2[1].x = aa.z; a2[1].y = aa.w;
    a2[2].x = ab.x; a2[2].y = ab.y; a2[3].x = ab.z; a2[3].y = ab.w;
  }

  const int e0 = offs[dst], e1 = offs[dst + 1];
  const f2 zf2 = {0.f, 0.f};
  f2 acc2[4];
#pragma unroll
  for (int j = 0; j < 4; j++) acc2[j] = zf2;
  float denom = 0.f;

  for (int base = e0; base < e1; base += 8) {
    int e = base + g;
    f2 v2[4];
    float lt;
    if (e < e1) {
      int src = csr[e];
      load8bf2(xl1 + (size_t)src * F1 + chbase, v2);
      f2 lt2 = zf2;
#pragma unroll
      for (int j = 0; j < 4; j++)
        lt2 = lrelu2(v2[j] + r2[j]) * a2[j] + lt2;    // pk_add/pk_mul/pk_fma
      lt = lt2.x + lt2.y;
    } else {
#pragma unroll
      for (int j = 0; j < 4; j++) v2[j] = zf2;
      lt = -1e30f;
    }
    lt += __shfl_xor(lt, 1, 64);
    lt += __shfl_xor(lt, 2, 64);
    lt += __shfl_xor(lt, 4, 64);
    float p = __expf(fminf(lt, 60.f));   // invalid groups -> exp(-huge)=0
    denom += p;
    f2 pv; pv.x = p; pv.y = p;
#pragma unroll
    for (int j = 0; j < 4; j++) acc2[j] = pv * v2[j] + acc2[j];  // pk_fma
  }

  // combine the 8 edge-groups (once per node)
#pragma unroll
  for (int m = 8; m <= 32; m <<= 1) {
    denom += __shfl_xor(denom, m, 64);
#pragma unroll
    for (int j = 0; j < 4; j++) {
      acc2[j].x += __shfl_xor(acc2[j].x, m, 64);
      acc2[j].y += __shfl_xor(acc2[j].y, m, 64);
    }
  }

  if (g == 0) {
    float inv = 1.f / (denom + EPS_A);
    __align__(16) bf16 ob[8];
#pragma unroll
    for (int j = 0; j < 4; j++) {
      float o0 = fmaxf(acc2[j].x * inv + par[P_BIAS1 + chbase + 2*j],     0.f);
      float o1 = fmaxf(acc2[j].y * inv + par[P_BIAS1 + chbase + 2*j + 1], 0.f);
      ob[2*j] = (bf16)o0; ob[2*j+1] = (bf16)o1;
    }
    *(uint4*)(hout + (size_t)dst * F1 + chbase) = *(uint4*)ob;
  }
}

// ---------------- layer-2 aggregation (packed-f32 math) ----------------
// 4 waves/block, wave = one dst. 8 groups x 8 lanes; lane holds 16 ch = 8 x f2.
__global__ __launch_bounds__(256, 4) void agg2_k(
    const bf16* __restrict__ xl2, const bf16* __restrict__ xr2,
    const float* __restrict__ par,
    const int* __restrict__ offs, const int* __restrict__ csr,
    bf16* __restrict__ h2) {
  const int dst = blockIdx.x * 4 + (threadIdx.x >> 6);
  if (dst >= N_NODES) return;
  const int lane = threadIdx.x & 63;
  const int g = lane >> 3;
  const int sl = lane & 7;
  const int chb = sl * 16;

  f2 r2[8], a2[8];
  load8bf2(xr2 + (size_t)dst * F2 + chb, r2);
  load8bf2(xr2 + (size_t)dst * F2 + chb + 8, r2 + 4);
#pragma unroll
  for (int j = 0; j < 4; j++) {
    float4 av = *(const float4*)(par + P_ATT2 + chb + 4*j);
    a2[2*j].x = av.x; a2[2*j].y = av.y; a2[2*j+1].x = av.z; a2[2*j+1].y = av.w;
  }

  const int e0 = offs[dst], e1 = offs[dst + 1];
  const f2 zf2 = {0.f, 0.f};
  f2 acc2[8];
#pragma unroll
  for (int j = 0; j < 8; j++) acc2[j] = zf2;
  float denom = 0.f;

  for (int base = e0; base < e1; base += 8) {
    int e = base + g;
    f2 v2[8];
    float lt;
    if (e < e1) {
      int src = csr[e];
      load8bf2(xl2 + (size_t)src * F2 + chb, v2);
      load8bf2(xl2 + (size_t)src * F2 + chb + 8, v2 + 4);
      f2 lt2 = zf2;
#pragma unroll
      for (int j = 0; j < 8; j++)
        lt2 = lrelu2(v2[j] + r2[j]) * a2[j] + lt2;
      lt = lt2.x + lt2.y;
    } else {
#pragma unroll
      for (int j = 0; j < 8; j++) v2[j] = zf2;
      lt = -1e30f;
    }
    lt += __shfl_xor(lt, 1, 64);
    lt += __shfl_xor(lt, 2, 64);
    lt += __shfl_xor(lt, 4, 64);
    float p = __expf(fminf(lt, 60.f));
    denom += p;
    f2 pv; pv.x = p; pv.y = p;
#pragma unroll
    for (int j = 0; j < 8; j++) acc2[j] = pv * v2[j] + acc2[j];
  }

#pragma unroll
  for (int m = 8; m <= 32; m <<= 1) {
    denom += __shfl_xor(denom, m, 64);
#pragma unroll
    for (int j = 0; j < 8; j++) {
      acc2[j].x += __shfl_xor(acc2[j].x, m, 64);
      acc2[j].y += __shfl_xor(acc2[j].y, m, 64);
    }
  }

  if (g == 0) {
    float inv = 1.f / (denom + EPS_A);
    __align__(16) bf16 ob[16];
#pragma unroll
    for (int j = 0; j < 8; j++) {
      float o0 = fmaxf(acc2[j].x * inv + par[P_BIAS2 + chb + 2*j],     0.f);
      float o1 = fmaxf(acc2[j].y * inv + par[P_BIAS2 + chb + 2*j + 1], 0.f);
      ob[2*j] = (bf16)o0; ob[2*j+1] = (bf16)o1;
    }
    *(uint4*)(h2 + (size_t)dst * F2 + chb)     = *(uint4*)ob;
    *(uint4*)(h2 + (size_t)dst * F2 + chb + 8) = *(uint4*)(ob + 8);
  }
}

// ---------------- pooling (batch is sorted) ----------------
__global__ void binit_k(int* __restrict__ gs, int* __restrict__ ge) {
  int g = threadIdx.x;
  if (g < NGRAPH) { gs[g] = INT_MAX; ge[g] = -1; }
}

// batch sorted -> graph boundaries are local transitions. No atomics.
__global__ void bounds_k(const int* __restrict__ batch,
                         int* __restrict__ gs, int* __restrict__ ge) {
  int n = blockIdx.x * 256 + threadIdx.x;
  if (n >= N_NODES) return;
  int b = batch[n];
  if (n == 0) {
    gs[b] = 0;
  } else {
    int bp = batch[n - 1];
    if (bp != b) { gs[b] = n; ge[bp] = n - 1; }
  }
  if (n == N_NODES - 1) ge[b] = N_NODES - 1;
}

__global__ __launch_bounds__(256) void pool_k(
    const bf16* __restrict__ h2, const int* __restrict__ gs,
    const int* __restrict__ ge, const int* __restrict__ flag,
    void* __restrict__ out) {
  const int g = blockIdx.x;
  const int t = threadIdx.x;
  const int c = t & 127, half = t >> 7;
  const int s = gs[g], e = ge[g];
  float sum = 0.f;
  for (int n = s + half; n <= e; n += 2)
    sum += (float)h2[(size_t)n * F2 + c];
  __shared__ float red[128];
  if (half == 1) red[c] = sum;
  __syncthreads();
  if (half == 0) {
    float tot = sum + red[c];
    float cnt = (e >= s) ? (float)(e - s + 1) : 1.f;
    float v = tot / cnt;
    if (*flag) ((float*)out)[g * F2 + c] = v;
    else       ((bf16*)out)[g * F2 + c] = (bf16)v;
  }
}

// ---------------- launch ----------------
extern "C" void kernel_launch(void* const* d_in, const int* in_sizes, int n_in,
                              void* d_out, int out_size, void* d_ws, size_t ws_size,
                              hipStream_t stream) {
  (void)in_sizes; (void)n_in; (void)out_size; (void)ws_size;
  const void* x     = d_in[0];
  const int*  ei    = (const int*)d_in[1];
  const int*  batch = (const int*)d_in[2];

  char* ws = (char*)d_ws;
  int*   flag = (int*)(ws + OFF_FLAG);
  float* par  = (float*)(ws + OFF_PAR);
  bf16* xl1 = (bf16*)(ws + OFF_XL1);
  bf16* xr1 = (bf16*)(ws + OFF_XR1);
  bf16* h   = (bf16*)(ws + OFF_H);
  bf16* xl2 = (bf16*)(ws + OFF_XL2);
  bf16* xr2 = (bf16*)(ws + OFF_XR2);
  bf16* h2  = (bf16*)(ws + OFF_H2);
  bf16* xb  = (bf16*)(ws + OFF_XB);
  bf16* wt1 = (bf16*)(ws + OFF_WT1);
  bf16* wt2 = (bf16*)(ws + OFF_WT2);
  int* cnt    = (int*)(ws + OFF_CNT);
  int* offs   = (int*)(ws + OFF_OFFS);
  int* cursor = (int*)(ws + OFF_CUR);
  int* csr    = (int*)(ws + OFF_CSR);
  int* gs     = (int*)(ws + OFF_GS);
  int* ge     = (int*)(ws + OFF_GE);

  hipMemsetAsync(cnt, 0, (size_t)N_NODES * 4, stream);

  detect_k<<<1, 64, 0, stream>>>(x, flag);

  CvtArgs ca;
  const int srcidx[12] = {3, 4, 5, 6, 7, 8, 9, 10, 11, 12, 13, 14};
  const int ns[12]     = {IN_F * F1, F1, IN_F * F1, F1, F1, F1,
                          F1 * F2, F2, F1 * F2, F2, F2, F2};
  const int doff[12]   = {P_WL1, P_BL1, P_WR1, P_BR1, P_ATT1, P_BIAS1,
                          P_WL2, P_BL2, P_WR2, P_BR2, P_ATT2, P_BIAS2};
  for (int i = 0; i < 12; i++) { ca.src[i] = d_in[srcidx[i]]; ca.n[i] = ns[i]; ca.dstoff[i] = doff[i]; }
  convert_k<<<dim3((F1 * F2 + 255) / 256, 12), 256, 0, stream>>>(ca, flag, par);

  xprep_k<<<(N_NODES * 64 + 255) / 256, 256, 0, stream>>>(flag, x, xb);
  wprep1_k<<<(512 * 64 + 255) / 256, 256, 0, stream>>>(flag, d_in[3], d_in[5], wt1);
  wprep2_k<<<(256 * 256 + 255) / 256, 256, 0, stream>>>(flag, d_in[9], d_in[11], wt2);

  const int ebl = (TOT_E + 255) / 256;
  const int gblk = (N_NODES + 31) / 32;   // 1563

  gemm1_mfma_k<<<gblk, 256, 0, stream>>>(xb, wt1, par, xl1, xr1);
  count_k<<<ebl, 256, 0, stream>>>(ei, cnt);
  scan_k<<<1, 1024, 0, stream>>>(cnt, offs, cursor);
  scatter_k<<<ebl, 256, 0, stream>>>(ei, cursor, csr);
  binit_k<<<1, 128, 0, stream>>>(gs, ge);
  bounds_k<<<(N_NODES + 255) / 256, 256, 0, stream>>>(batch, gs, ge);
  agg1_k<<<N_NODES, 256, 0, stream>>>(xl1, xr1, par, offs, csr, h);
  gemm2_mfma_k<<<gblk, 256, 0, stream>>>(h, wt2, par, xl2, xr2);
  agg2_k<<<(N_NODES + 3) / 4, 256, 0, stream>>>(xl2, xr2, par, offs, csr, h2);
  pool_k<<<NGRAPH, 256, 0, stream>>>(h2, gs, ge, flag, d_out);
}

// Round 7
// 552.913 us; speedup vs baseline: 1.0741x; 1.0741x over previous
//
#include <hip/hip_runtime.h>
#include <hip/hip_bf16.h>
#include <limits.h>

// ---------------- problem constants ----------------
#define N_NODES 50000
#define N_EDGES 800000
#define TOT_E   (N_EDGES + N_NODES)   // with self loops
#define IN_F    38
#define HIDC    64
#define NH      4
#define F1      256                    // NH*HIDC
#define F2      128                    // OUT
#define NGRAPH  128
#define NEG_SLOPE 0.2f
#define EPS_A   1e-16f

typedef __hip_bfloat16 bf16;
typedef __attribute__((ext_vector_type(8))) short short8;
typedef __attribute__((ext_vector_type(4))) float f32x4;
typedef __attribute__((ext_vector_type(2))) float f2;   // lowers to VOP3P v_pk_*_f32

// ---------------- ws layout ----------------
constexpr size_t al256(size_t x) { return (x + 255) & ~(size_t)255; }

// converted-params element offsets (f32 elements) — contiguous in this order
#define P_WL1   0
#define P_BL1   (P_WL1 + IN_F * F1)        // 9728
#define P_WR1   (P_BL1 + F1)               // 9984
#define P_BR1   (P_WR1 + IN_F * F1)        // 19712
#define P_ATT1  (P_BR1 + F1)               // 19968
#define P_BIAS1 (P_ATT1 + F1)              // 20224
#define P_WL2   (P_BIAS1 + F1)             // 20480
#define P_BL2   (P_WL2 + F1 * F2)          // 53248
#define P_WR2   (P_BL2 + F2)               // 53376
#define P_BR2   (P_WR2 + F1 * F2)          // 86144
#define P_ATT2  (P_BR2 + F2)               // 86272
#define P_BIAS2 (P_ATT2 + F2)              // 86400
#define P_TOTAL (P_BIAS2 + F2)             // 86528 = 338*256 exactly

constexpr size_t OFF_PAR  = 256;
constexpr size_t OFF_XL1  = OFF_PAR + al256((size_t)P_TOTAL * 4);   // reused as h2 later
constexpr size_t OFF_XR1  = OFF_XL1 + al256((size_t)N_NODES * F1 * 2);
constexpr size_t OFF_H    = OFF_XR1 + al256((size_t)N_NODES * F1 * 2);
constexpr size_t OFF_XL2  = OFF_H   + al256((size_t)N_NODES * F1 * 2);
constexpr size_t OFF_XR2  = OFF_XL2 + al256((size_t)N_NODES * F2 * 2);
constexpr size_t OFF_CNT  = OFF_XR2 + al256((size_t)N_NODES * F2 * 2);
constexpr size_t OFF_OFFS = OFF_CNT + al256((size_t)N_NODES * 4);
constexpr size_t OFF_CUR  = OFF_OFFS+ al256((size_t)(N_NODES + 1) * 4);
constexpr size_t OFF_CSR  = OFF_CUR + al256((size_t)(N_NODES + 1) * 4);
constexpr size_t OFF_GS   = OFF_CSR + al256((size_t)TOT_E * 4);
constexpr size_t OFF_GE   = OFF_GS  + al256((size_t)NGRAPH * 4);    // adjacent to GS
constexpr size_t OFF_WT1  = OFF_GE  + al256((size_t)NGRAPH * 4);    // 512x64 bf16
constexpr size_t OFF_WT2  = OFF_WT1 + al256((size_t)512 * 64 * 2);  // 256x256 bf16
constexpr size_t OFF_H2   = OFF_XL1;  // xl1 dead after agg1
constexpr size_t OFF_XB   = OFF_H;    // xb (N x 64 bf16) dead before agg1 writes h

// ---------------- helpers ----------------
// 16B (8 bf16) -> 4 x f2; pairs are (ch 2i, ch 2i+1)
__device__ __forceinline__ void load8bf2(const bf16* __restrict__ p, f2* f) {
  uint4 q = *(const uint4*)p;
  unsigned v[4] = {q.x, q.y, q.z, q.w};
#pragma unroll
  for (int i = 0; i < 4; i++) {
    f2 t;
    t.x = __uint_as_float(v[i] << 16);
    t.y = __uint_as_float(v[i] & 0xffff0000u);
    f[i] = t;
  }
}

// leaky_relu(s) = 0.6*s + 0.4*|s|
__device__ __forceinline__ f2 lrelu2(f2 s) {
  f2 as;
  as.x = __uint_as_float(__float_as_uint(s.x) & 0x7fffffffu);
  as.y = __uint_as_float(__float_as_uint(s.y) & 0x7fffffffu);
  return 0.6f * s + 0.4f * as;
}

// wave-cooperative dtype sniff: 1 = inputs are f32, 0 = bf16.
// f32 misread as bf16 halfwords: ~half have wild exponents; bf16 N(0,1): none.
__device__ __forceinline__ int detect_f32_wave(const void* __restrict__ x) {
  const unsigned short* u = (const unsigned short*)x;
  unsigned short b = u[threadIdx.x & 63];
  int e = (b >> 7) & 0xFF;
  unsigned long long m = __ballot(!((e == 0) || (e >= 96 && e <= 158)));
  return __popcll(m) > 8;
}

// ---------------- fused prep kernel ----------------
// block ranges: [0,338) convert params | [..,+12500) xprep | +128 wprep1
// | +256 wprep2 | +196 bounds | +3321 count
#define B_CVT  338
#define B_XP   12500
#define B_W1   128
#define B_W2   256
#define B_BND  196
#define B_CNT  3321

struct PrepArgs {
  const void* x;
  const void* src[12];     // Wl1,bl1,Wr1,br1,att1,bias1,Wl2,bl2,Wr2,br2,att2,bias2
  const int* ei;
  const int* batch;
};

__global__ __launch_bounds__(256) void prep_k(
    PrepArgs a, float* __restrict__ par, bf16* __restrict__ xb,
    bf16* __restrict__ wt1, bf16* __restrict__ wt2,
    int* __restrict__ gs, int* __restrict__ ge, int* __restrict__ cnt) {
  int b = blockIdx.x;
  const int tid = threadIdx.x;

  if (b < B_CVT) {                       // ---- param convert -> f32 ----
    const int flag = detect_f32_wave(a.x);
    int idx = b * 256 + tid;             // [0, P_TOTAL)
    const void* p; int base;
    if      (idx < P_BL1)  { p = a.src[0];  base = P_WL1; }
    else if (idx < P_WR1)  { p = a.src[1];  base = P_BL1; }
    else if (idx < P_BR1)  { p = a.src[2];  base = P_WR1; }
    else if (idx < P_ATT1) { p = a.src[3];  base = P_BR1; }
    else if (idx < P_BIAS1){ p = a.src[4];  base = P_ATT1; }
    else if (idx < P_WL2)  { p = a.src[5];  base = P_BIAS1; }
    else if (idx < P_BL2)  { p = a.src[6];  base = P_WL2; }
    else if (idx < P_WR2)  { p = a.src[7];  base = P_BL2; }
    else if (idx < P_BR2)  { p = a.src[8];  base = P_WR2; }
    else if (idx < P_ATT2) { p = a.src[9];  base = P_BR2; }
    else if (idx < P_BIAS2){ p = a.src[10]; base = P_ATT2; }
    else                   { p = a.src[11]; base = P_BIAS2; }
    int li = idx - base;
    par[idx] = flag ? ((const float*)p)[li] : (float)((const bf16*)p)[li];
    return;
  }
  b -= B_CVT;
  if (b < B_XP) {                        // ---- x -> xb (N x 64, zero-pad K) ----
    const int flag = detect_f32_wave(a.x);
    int i = b * 256 + tid;               // n*64 + k
    int n = i >> 6, k = i & 63;
    float v = 0.f;
    if (k < IN_F) {
      int idx = n * IN_F + k;
      v = flag ? ((const float*)a.x)[idx] : (float)((const bf16*)a.x)[idx];
    }
    xb[i] = (bf16)v;
    return;
  }
  b -= B_XP;
  if (b < B_W1) {                        // ---- Wt1[n][k] 512x64 ----
    const int flag = detect_f32_wave(a.x);
    int i = b * 256 + tid;
    int n = i >> 6, k = i & 63;
    float v = 0.f;
    if (k < IN_F) {
      const void* W = (n < F1) ? a.src[0] : a.src[2];
      int col = (n < F1) ? n : n - F1;
      int idx = k * F1 + col;
      v = flag ? ((const float*)W)[idx] : (float)((const bf16*)W)[idx];
    }
    wt1[i] = (bf16)v;
    return;
  }
  b -= B_W1;
  if (b < B_W2) {                        // ---- Wt2[n][k] 256x256 ----
    const int flag = detect_f32_wave(a.x);
    int i = b * 256 + tid;
    int n = i >> 8, k = i & 255;
    const void* W = (n < F2) ? a.src[6] : a.src[8];
    int col = (n < F2) ? n : n - F2;
    int idx = k * F2 + col;
    float v = flag ? ((const float*)W)[idx] : (float)((const bf16*)W)[idx];
    wt2[i] = (bf16)v;
    return;
  }
  b -= B_W2;
  if (b < B_BND) {                       // ---- graph bounds (batch sorted) ----
    int n = b * 256 + tid;
    if (n >= N_NODES) return;
    int bb = a.batch[n];
    if (n == 0) gs[bb] = 0;
    else {
      int bp = a.batch[n - 1];
      if (bp != bb) { gs[bb] = n; ge[bp] = n - 1; }
    }
    if (n == N_NODES - 1) ge[bb] = N_NODES - 1;
    return;
  }
  b -= B_BND;
  {                                      // ---- degree count ----
    int e = b * 256 + tid;
    if (e >= TOT_E) return;
    int dst = (e < N_EDGES) ? a.ei[N_EDGES + e] : (e - N_EDGES);
    atomicAdd(&cnt[dst], 1);
  }
}

// ---------------- GEMM 1 (MFMA): xb(N,64) @ Wt1^T -> xl1|xr1 (N,256 each) ----------------
__global__ __launch_bounds__(256) void gemm1_mfma_k(
    const bf16* __restrict__ xb, const bf16* __restrict__ wt1,
    const float* __restrict__ par,
    bf16* __restrict__ xl1, bf16* __restrict__ xr1) {
  const int w = threadIdx.x >> 6, lane = threadIdx.x & 63;
  const int m0 = blockIdx.x * 32 + (w & 1) * 16;
  const int colbase = (w >> 1) * 256;
  const int lm = lane & 15, lk = lane >> 4;

  int arow = m0 + lm; if (arow >= N_NODES) arow = N_NODES - 1;
  const short8 a0 = *(const short8*)(xb + (size_t)arow * 64 + lk * 8);
  const short8 a1 = *(const short8*)(xb + (size_t)arow * 64 + 32 + lk * 8);

  f32x4 acc[16];
  const f32x4 z = {0.f, 0.f, 0.f, 0.f};
#pragma unroll
  for (int nt = 0; nt < 16; nt++) acc[nt] = z;

#pragma unroll
  for (int nt = 0; nt < 16; nt++) {
    int n = colbase + nt * 16 + lm;
    short8 b0 = *(const short8*)(wt1 + (size_t)n * 64 + lk * 8);
    short8 b1 = *(const short8*)(wt1 + (size_t)n * 64 + 32 + lk * 8);
    acc[nt] = __builtin_amdgcn_mfma_f32_16x16x32_bf16(a0, b0, acc[nt], 0, 0, 0);
    acc[nt] = __builtin_amdgcn_mfma_f32_16x16x32_bf16(a1, b1, acc[nt], 0, 0, 0);
  }

  const int r0 = m0 + (lane >> 4) * 4;
#pragma unroll
  for (int nt = 0; nt < 16; nt++) {
    int col = colbase + nt * 16 + lm;
    bf16* dst = (col < F1) ? xl1 : xr1;
    int c = (col < F1) ? col : col - F1;
    float bv = (col < F1) ? par[P_BL1 + c] : par[P_BR1 + c];
#pragma unroll
    for (int reg = 0; reg < 4; reg++) {
      int row = r0 + reg;
      if (row < N_NODES)
        dst[(size_t)row * F1 + c] = (bf16)(acc[nt][reg] + bv);
    }
  }
}

// ---------------- GEMM 2 (MFMA): h(N,256) @ Wt2^T -> xl2|xr2 (N,128 each) ----------------
__global__ __launch_bounds__(256) void gemm2_mfma_k(
    const bf16* __restrict__ h, const bf16* __restrict__ wt2,
    const float* __restrict__ par,
    bf16* __restrict__ xl2, bf16* __restrict__ xr2) {
  const int w = threadIdx.x >> 6, lane = threadIdx.x & 63;
  const int m0 = blockIdx.x * 32 + (w & 1) * 16;
  const int colbase = (w >> 1) * 128;
  const int lm = lane & 15, lk = lane >> 4;

  int arow = m0 + lm; if (arow >= N_NODES) arow = N_NODES - 1;
  const bf16* hrow = h + (size_t)arow * F1 + lk * 8;

  f32x4 acc[8];
  const f32x4 z = {0.f, 0.f, 0.f, 0.f};
#pragma unroll
  for (int nt = 0; nt < 8; nt++) acc[nt] = z;

#pragma unroll
  for (int kk = 0; kk < 256; kk += 32) {
    short8 a = *(const short8*)(hrow + kk);
#pragma unroll
    for (int nt = 0; nt < 8; nt++) {
      int n = colbase + nt * 16 + lm;
      short8 b = *(const short8*)(wt2 + (size_t)n * 256 + kk + lk * 8);
      acc[nt] = __builtin_amdgcn_mfma_f32_16x16x32_bf16(a, b, acc[nt], 0, 0, 0);
    }
  }

  const int r0 = m0 + (lane >> 4) * 4;
#pragma unroll
  for (int nt = 0; nt < 8; nt++) {
    int col = colbase + nt * 16 + lm;
    bf16* dst = (col < F2) ? xl2 : xr2;
    int c = (col < F2) ? col : col - F2;
    float bv = (col < F2) ? par[P_BL2 + c] : par[P_BR2 + c];
#pragma unroll
    for (int reg = 0; reg < 4; reg++) {
      int row = r0 + reg;
      if (row < N_NODES)
        dst[(size_t)row * F2 + c] = (bf16)(acc[nt][reg] + bv);
    }
  }
}

// ---------------- CSR scan + scatter ----------------
__global__ __launch_bounds__(1024) void scan_k(const int* __restrict__ cnt,
                                               int* __restrict__ offs,
                                               int* __restrict__ cursor) {
  __shared__ int wsum[16];
  __shared__ int carry_s;
  const int t = threadIdx.x;
  const int lane = t & 63, w = t >> 6;
  if (t == 0) carry_s = 0;
  __syncthreads();
  for (int base = 0; base < N_NODES; base += 1024) {
    int idx = base + t;
    int v = (idx < N_NODES) ? cnt[idx] : 0;
    int s = v;
#pragma unroll
    for (int off = 1; off < 64; off <<= 1) {
      int u = __shfl_up(s, off, 64);
      if (lane >= off) s += u;
    }
    if (lane == 63) wsum[w] = s;
    __syncthreads();
    int prefix = carry_s;
    for (int i = 0; i < w; i++) prefix += wsum[i];
    int excl = prefix + s - v;
    if (idx < N_NODES) { offs[idx] = excl; cursor[idx] = excl; }
    __syncthreads();
    if (t == 1023) carry_s = prefix + s;
    __syncthreads();
  }
  if (t == 0) offs[N_NODES] = carry_s;
}

__global__ void scatter_k(const int* __restrict__ ei, int* __restrict__ cursor,
                          int* __restrict__ csr) {
  int e = blockIdx.x * 256 + threadIdx.x;
  if (e >= TOT_E) return;
  int src, dst;
  if (e < N_EDGES) { src = ei[e]; dst = ei[N_EDGES + e]; }
  else             { src = dst = e - N_EDGES; }
  int pos = atomicAdd(&cursor[dst], 1);
  csr[pos] = src;
}

// ---------------- layer-1 aggregation: ONE wave per dst ----------------
// Wave: 2 groups x 32 lanes. Group g handles edge base+g; lane sl holds
// channels sl*8..sl*8+7 (16B) -> 32 lanes cover the full 256-ch row.
// Head = sl>>3; logit reduce = 3 shfl within the 8-lane head subgroup.
__global__ __launch_bounds__(256, 4) void agg1_k(
    const bf16* __restrict__ xl1, const bf16* __restrict__ xr1,
    const float* __restrict__ par,
    const int* __restrict__ offs, const int* __restrict__ csr,
    bf16* __restrict__ hout) {
  const int dst = blockIdx.x * 4 + (threadIdx.x >> 6);
  if (dst >= N_NODES) return;
  const int lane = threadIdx.x & 63;
  const int g = lane >> 5;        // 2 edge groups
  const int sl = lane & 31;
  const int chbase = sl * 8;

  f2 r2[4], a2[4];
  load8bf2(xr1 + (size_t)dst * F1 + chbase, r2);
  {
    float4 aa = *(const float4*)(par + P_ATT1 + chbase);
    float4 ab = *(const float4*)(par + P_ATT1 + chbase + 4);
    a2[0].x = aa.x; a2[0].y = aa.y; a2[1].x = aa.z; a2[1].y = aa.w;
    a2[2].x = ab.x; a2[2].y = ab.y; a2[3].x = ab.z; a2[3].y = ab.w;
  }

  const int e0 = offs[dst], e1 = offs[dst + 1];
  const f2 zf2 = {0.f, 0.f};
  f2 acc2[4];
#pragma unroll
  for (int j = 0; j < 4; j++) acc2[j] = zf2;
  float denom = 0.f;

  for (int base = e0; base < e1; base += 2) {
    int e = base + g;
    f2 v2[4];
    float lt;
    if (e < e1) {
      int src = csr[e];
      load8bf2(xl1 + (size_t)src * F1 + chbase, v2);
      f2 lt2 = zf2;
#pragma unroll
      for (int j = 0; j < 4; j++)
        lt2 = lrelu2(v2[j] + r2[j]) * a2[j] + lt2;
      lt = lt2.x + lt2.y;
    } else {
#pragma unroll
      for (int j = 0; j < 4; j++) v2[j] = zf2;
      lt = -1e30f;
    }
    // per-head reduce over this lane's 8-lane head subgroup
    lt += __shfl_xor(lt, 1, 64);
    lt += __shfl_xor(lt, 2, 64);
    lt += __shfl_xor(lt, 4, 64);
    float p = __expf(fminf(lt, 60.f));   // logits O(1); invalid group -> 0
    denom += p;
    f2 pv; pv.x = p; pv.y = p;
#pragma unroll
    for (int j = 0; j < 4; j++) acc2[j] = pv * v2[j] + acc2[j];
  }

  // combine the 2 edge groups (lane ^ 32 has same channels & head)
  denom += __shfl_xor(denom, 32, 64);
#pragma unroll
  for (int j = 0; j < 4; j++) {
    acc2[j].x += __shfl_xor(acc2[j].x, 32, 64);
    acc2[j].y += __shfl_xor(acc2[j].y, 32, 64);
  }

  if (g == 0) {
    float inv = 1.f / (denom + EPS_A);
    __align__(16) bf16 ob[8];
#pragma unroll
    for (int j = 0; j < 4; j++) {
      float o0 = fmaxf(acc2[j].x * inv + par[P_BIAS1 + chbase + 2*j],     0.f);
      float o1 = fmaxf(acc2[j].y * inv + par[P_BIAS1 + chbase + 2*j + 1], 0.f);
      ob[2*j] = (bf16)o0; ob[2*j+1] = (bf16)o1;
    }
    *(uint4*)(hout + (size_t)dst * F1 + chbase) = *(uint4*)ob;
  }
}

// ---------------- layer-2 aggregation (unchanged structure) ----------------
__global__ __launch_bounds__(256, 4) void agg2_k(
    const bf16* __restrict__ xl2, const bf16* __restrict__ xr2,
    const float* __restrict__ par,
    const int* __restrict__ offs, const int* __restrict__ csr,
    bf16* __restrict__ h2) {
  const int dst = blockIdx.x * 4 + (threadIdx.x >> 6);
  if (dst >= N_NODES) return;
  const int lane = threadIdx.x & 63;
  const int g = lane >> 3;
  const int sl = lane & 7;
  const int chb = sl * 16;

  f2 r2[8], a2[8];
  load8bf2(xr2 + (size_t)dst * F2 + chb, r2);
  load8bf2(xr2 + (size_t)dst * F2 + chb + 8, r2 + 4);
#pragma unroll
  for (int j = 0; j < 4; j++) {
    float4 av = *(const float4*)(par + P_ATT2 + chb + 4*j);
    a2[2*j].x = av.x; a2[2*j].y = av.y; a2[2*j+1].x = av.z; a2[2*j+1].y = av.w;
  }

  const int e0 = offs[dst], e1 = offs[dst + 1];
  const f2 zf2 = {0.f, 0.f};
  f2 acc2[8];
#pragma unroll
  for (int j = 0; j < 8; j++) acc2[j] = zf2;
  float denom = 0.f;

  for (int base = e0; base < e1; base += 8) {
    int e = base + g;
    f2 v2[8];
    float lt;
    if (e < e1) {
      int src = csr[e];
      load8bf2(xl2 + (size_t)src * F2 + chb, v2);
      load8bf2(xl2 + (size_t)src * F2 + chb + 8, v2 + 4);
      f2 lt2 = zf2;
#pragma unroll
      for (int j = 0; j < 8; j++)
        lt2 = lrelu2(v2[j] + r2[j]) * a2[j] + lt2;
      lt = lt2.x + lt2.y;
    } else {
#pragma unroll
      for (int j = 0; j < 8; j++) v2[j] = zf2;
      lt = -1e30f;
    }
    lt += __shfl_xor(lt, 1, 64);
    lt += __shfl_xor(lt, 2, 64);
    lt += __shfl_xor(lt, 4, 64);
    float p = __expf(fminf(lt, 60.f));
    denom += p;
    f2 pv; pv.x = p; pv.y = p;
#pragma unroll
    for (int j = 0; j < 8; j++) acc2[j] = pv * v2[j] + acc2[j];
  }

#pragma unroll
  for (int m = 8; m <= 32; m <<= 1) {
    denom += __shfl_xor(denom, m, 64);
#pragma unroll
    for (int j = 0; j < 8; j++) {
      acc2[j].x += __shfl_xor(acc2[j].x, m, 64);
      acc2[j].y += __shfl_xor(acc2[j].y, m, 64);
    }
  }

  if (g == 0) {
    float inv = 1.f / (denom + EPS_A);
    __align__(16) bf16 ob[16];
#pragma unroll
    for (int j = 0; j < 8; j++) {
      float o0 = fmaxf(acc2[j].x * inv + par[P_BIAS2 + chb + 2*j],     0.f);
      float o1 = fmaxf(acc2[j].y * inv + par[P_BIAS2 + chb + 2*j + 1], 0.f);
      ob[2*j] = (bf16)o0; ob[2*j+1] = (bf16)o1;
    }
    *(uint4*)(h2 + (size_t)dst * F2 + chb)     = *(uint4*)ob;
    *(uint4*)(h2 + (size_t)dst * F2 + chb + 8) = *(uint4*)(ob + 8);
  }
}

// ---------------- pooling ----------------
__global__ __launch_bounds__(256) void pool_k(
    const bf16* __restrict__ h2, const int* __restrict__ gs,
    const int* __restrict__ ge, const void* __restrict__ x,
    void* __restrict__ out) {
  const int flag = detect_f32_wave(x);
  const int g = blockIdx.x;
  const int t = threadIdx.x;
  const int c = t & 127, half = t >> 7;
  int s = gs[g], e = ge[g];
  if (s < 0 || e < s) { s = 0; e = -1; }   // empty graph (memset-init) -> 0
  float sum = 0.f;
  for (int n = s + half; n <= e; n += 2)
    sum += (float)h2[(size_t)n * F2 + c];
  __shared__ float red[128];
  if (half == 1) red[c] = sum;
  __syncthreads();
  if (half == 0) {
    float tot = sum + red[c];
    float cnt = (e >= s) ? (float)(e - s + 1) : 1.f;
    float v = tot / cnt;
    if (flag) ((float*)out)[g * F2 + c] = v;
    else      ((bf16*)out)[g * F2 + c] = (bf16)v;
  }
}

// ---------------- launch ----------------
extern "C" void kernel_launch(void* const* d_in, const int* in_sizes, int n_in,
                              void* d_out, int out_size, void* d_ws, size_t ws_size,
                              hipStream_t stream) {
  (void)in_sizes; (void)n_in; (void)out_size; (void)ws_size;
  const void* x     = d_in[0];
  const int*  ei    = (const int*)d_in[1];
  const int*  batch = (const int*)d_in[2];

  char* ws = (char*)d_ws;
  float* par  = (float*)(ws + OFF_PAR);
  bf16* xl1 = (bf16*)(ws + OFF_XL1);
  bf16* xr1 = (bf16*)(ws + OFF_XR1);
  bf16* h   = (bf16*)(ws + OFF_H);
  bf16* xl2 = (bf16*)(ws + OFF_XL2);
  bf16* xr2 = (bf16*)(ws + OFF_XR2);
  bf16* h2  = (bf16*)(ws + OFF_H2);
  bf16* xb  = (bf16*)(ws + OFF_XB);
  bf16* wt1 = (bf16*)(ws + OFF_WT1);
  bf16* wt2 = (bf16*)(ws + OFF_WT2);
  int* cnt    = (int*)(ws + OFF_CNT);
  int* offs   = (int*)(ws + OFF_OFFS);
  int* cursor = (int*)(ws + OFF_CUR);
  int* csr    = (int*)(ws + OFF_CSR);
  int* gs     = (int*)(ws + OFF_GS);
  int* ge     = (int*)(ws + OFF_GE);

  hipMemsetAsync(cnt, 0, (size_t)N_NODES * 4, stream);
  hipMemsetAsync(gs, 0xFF, (size_t)(OFF_WT1 - OFF_GS), stream);  // gs/ge = -1

  PrepArgs pa;
  pa.x = x; pa.ei = ei; pa.batch = batch;
  for (int i = 0; i < 12; i++) pa.src[i] = d_in[3 + i];
  const int prep_blocks = B_CVT + B_XP + B_W1 + B_W2 + B_BND + B_CNT;
  prep_k<<<prep_blocks, 256, 0, stream>>>(pa, par, xb, wt1, wt2, gs, ge, cnt);

  scan_k<<<1, 1024, 0, stream>>>(cnt, offs, cursor);
  scatter_k<<<(TOT_E + 255) / 256, 256, 0, stream>>>(ei, cursor, csr);

  const int gblk = (N_NODES + 31) / 32;   // 1563
  gemm1_mfma_k<<<gblk, 256, 0, stream>>>(xb, wt1, par, xl1, xr1);
  agg1_k<<<(N_NODES + 3) / 4, 256, 0, stream>>>(xl1, xr1, par, offs, csr, h);
  gemm2_mfma_k<<<gblk, 256, 0, stream>>>(h, wt2, par, xl2, xr2);
  agg2_k<<<(N_NODES + 3) / 4, 256, 0, stream>>>(xl2, xr2, par, offs, csr, h2);
  pool_k<<<NGRAPH, 256, 0, stream>>>(h2, gs, ge, x, d_out);
}

// Round 8
// 520.471 us; speedup vs baseline: 1.1410x; 1.0623x over previous
//
#include <hip/hip_runtime.h>
#include <hip/hip_bf16.h>
#include <limits.h>

// ---------------- problem constants ----------------
#define N_NODES 50000
#define N_EDGES 800000
#define TOT_E   (N_EDGES + N_NODES)   // with self loops
#define IN_F    38
#define HIDC    64
#define NH      4
#define F1      256                    // NH*HIDC
#define F2      128                    // OUT
#define NGRAPH  128
#define NEG_SLOPE 0.2f
#define EPS_A   1e-16f

typedef __hip_bfloat16 bf16;
typedef __attribute__((ext_vector_type(8))) short short8;
typedef __attribute__((ext_vector_type(4))) float f32x4;
typedef __attribute__((ext_vector_type(2))) float f2;   // lowers to VOP3P v_pk_*_f32

// ---------------- ws layout ----------------
constexpr size_t al256(size_t x) { return (x + 255) & ~(size_t)255; }

// converted-params element offsets (f32 elements) — contiguous in this order
#define P_WL1   0
#define P_BL1   (P_WL1 + IN_F * F1)        // 9728
#define P_WR1   (P_BL1 + F1)               // 9984
#define P_BR1   (P_WR1 + IN_F * F1)        // 19712
#define P_ATT1  (P_BR1 + F1)               // 19968
#define P_BIAS1 (P_ATT1 + F1)              // 20224
#define P_WL2   (P_BIAS1 + F1)             // 20480
#define P_BL2   (P_WL2 + F1 * F2)          // 53248
#define P_WR2   (P_BL2 + F2)               // 53376
#define P_BR2   (P_WR2 + F1 * F2)          // 86144
#define P_ATT2  (P_BR2 + F2)               // 86272
#define P_BIAS2 (P_ATT2 + F2)              // 86400
#define P_TOTAL (P_BIAS2 + F2)             // 86528 = 338*256 exactly

constexpr size_t OFF_PAR  = 256;
constexpr size_t OFF_XL1  = OFF_PAR + al256((size_t)P_TOTAL * 4);   // reused as h2 later
constexpr size_t OFF_XR1  = OFF_XL1 + al256((size_t)N_NODES * F1 * 2);
constexpr size_t OFF_H    = OFF_XR1 + al256((size_t)N_NODES * F1 * 2);
constexpr size_t OFF_XL2  = OFF_H   + al256((size_t)N_NODES * F1 * 2);
constexpr size_t OFF_XR2  = OFF_XL2 + al256((size_t)N_NODES * F2 * 2);
constexpr size_t OFF_CNT  = OFF_XR2 + al256((size_t)N_NODES * F2 * 2);
constexpr size_t OFF_OFFS = OFF_CNT + al256((size_t)N_NODES * 4);
constexpr size_t OFF_CUR  = OFF_OFFS+ al256((size_t)(N_NODES + 1) * 4);
constexpr size_t OFF_CSR  = OFF_CUR + al256((size_t)(N_NODES + 1) * 4);
constexpr size_t OFF_GS   = OFF_CSR + al256((size_t)TOT_E * 4);
constexpr size_t OFF_GE   = OFF_GS  + al256((size_t)NGRAPH * 4);    // adjacent to GS
constexpr size_t OFF_WT1  = OFF_GE  + al256((size_t)NGRAPH * 4);    // 512x64 bf16
constexpr size_t OFF_WT2  = OFF_WT1 + al256((size_t)512 * 64 * 2);  // 256x256 bf16
constexpr size_t OFF_BS   = OFF_WT2 + al256((size_t)256 * 256 * 2); // 49 block sums
constexpr size_t OFF_BO   = OFF_BS  + al256(64 * 4);                // 49 block offsets
constexpr size_t OFF_H2   = OFF_XL1;  // xl1 dead after agg1
constexpr size_t OFF_XB   = OFF_H;    // xb (N x 64 bf16) dead before agg1 writes h

#define SCAN_BLKS 49   // ceil(50000/1024)

// ---------------- helpers ----------------
// 16B (8 bf16) -> 4 x f2; pairs are (ch 2i, ch 2i+1)
__device__ __forceinline__ void load8bf2(const bf16* __restrict__ p, f2* f) {
  uint4 q = *(const uint4*)p;
  unsigned v[4] = {q.x, q.y, q.z, q.w};
#pragma unroll
  for (int i = 0; i < 4; i++) {
    f2 t;
    t.x = __uint_as_float(v[i] << 16);
    t.y = __uint_as_float(v[i] & 0xffff0000u);
    f[i] = t;
  }
}

// leaky_relu(s) = 0.6*s + 0.4*|s|
__device__ __forceinline__ f2 lrelu2(f2 s) {
  f2 as;
  as.x = __uint_as_float(__float_as_uint(s.x) & 0x7fffffffu);
  as.y = __uint_as_float(__float_as_uint(s.y) & 0x7fffffffu);
  return 0.6f * s + 0.4f * as;
}

// wave-cooperative dtype sniff: 1 = inputs are f32, 0 = bf16.
__device__ __forceinline__ int detect_f32_wave(const void* __restrict__ x) {
  const unsigned short* u = (const unsigned short*)x;
  unsigned short b = u[threadIdx.x & 63];
  int e = (b >> 7) & 0xFF;
  unsigned long long m = __ballot(!((e == 0) || (e >= 96 && e <= 158)));
  return __popcll(m) > 8;
}

// ---------------- fused prep kernel ----------------
#define B_CVT  338
#define B_XP   12500
#define B_W1   128
#define B_W2   256
#define B_BND  196
#define B_CNT  3321

struct PrepArgs {
  const void* x;
  const void* src[12];     // Wl1,bl1,Wr1,br1,att1,bias1,Wl2,bl2,Wr2,br2,att2,bias2
  const int* ei;
  const int* batch;
};

__global__ __launch_bounds__(256) void prep_k(
    PrepArgs a, float* __restrict__ par, bf16* __restrict__ xb,
    bf16* __restrict__ wt1, bf16* __restrict__ wt2,
    int* __restrict__ gs, int* __restrict__ ge, int* __restrict__ cnt) {
  int b = blockIdx.x;
  const int tid = threadIdx.x;

  if (b < B_CVT) {                       // ---- param convert -> f32 ----
    const int flag = detect_f32_wave(a.x);
    int idx = b * 256 + tid;             // [0, P_TOTAL)
    const void* p; int base;
    if      (idx < P_BL1)  { p = a.src[0];  base = P_WL1; }
    else if (idx < P_WR1)  { p = a.src[1];  base = P_BL1; }
    else if (idx < P_BR1)  { p = a.src[2];  base = P_WR1; }
    else if (idx < P_ATT1) { p = a.src[3];  base = P_BR1; }
    else if (idx < P_BIAS1){ p = a.src[4];  base = P_ATT1; }
    else if (idx < P_WL2)  { p = a.src[5];  base = P_BIAS1; }
    else if (idx < P_BL2)  { p = a.src[6];  base = P_WL2; }
    else if (idx < P_WR2)  { p = a.src[7];  base = P_BL2; }
    else if (idx < P_BR2)  { p = a.src[8];  base = P_WR2; }
    else if (idx < P_ATT2) { p = a.src[9];  base = P_BR2; }
    else if (idx < P_BIAS2){ p = a.src[10]; base = P_ATT2; }
    else                   { p = a.src[11]; base = P_BIAS2; }
    int li = idx - base;
    par[idx] = flag ? ((const float*)p)[li] : (float)((const bf16*)p)[li];
    return;
  }
  b -= B_CVT;
  if (b < B_XP) {                        // ---- x -> xb (N x 64, zero-pad K) ----
    const int flag = detect_f32_wave(a.x);
    int i = b * 256 + tid;               // n*64 + k
    int n = i >> 6, k = i & 63;
    float v = 0.f;
    if (k < IN_F) {
      int idx = n * IN_F + k;
      v = flag ? ((const float*)a.x)[idx] : (float)((const bf16*)a.x)[idx];
    }
    xb[i] = (bf16)v;
    return;
  }
  b -= B_XP;
  if (b < B_W1) {                        // ---- Wt1[n][k] 512x64 ----
    const int flag = detect_f32_wave(a.x);
    int i = b * 256 + tid;
    int n = i >> 6, k = i & 63;
    float v = 0.f;
    if (k < IN_F) {
      const void* W = (n < F1) ? a.src[0] : a.src[2];
      int col = (n < F1) ? n : n - F1;
      int idx = k * F1 + col;
      v = flag ? ((const float*)W)[idx] : (float)((const bf16*)W)[idx];
    }
    wt1[i] = (bf16)v;
    return;
  }
  b -= B_W1;
  if (b < B_W2) {                        // ---- Wt2[n][k] 256x256 ----
    const int flag = detect_f32_wave(a.x);
    int i = b * 256 + tid;
    int n = i >> 8, k = i & 255;
    const void* W = (n < F2) ? a.src[6] : a.src[8];
    int col = (n < F2) ? n : n - F2;
    int idx = k * F2 + col;
    float v = flag ? ((const float*)W)[idx] : (float)((const bf16*)W)[idx];
    wt2[i] = (bf16)v;
    return;
  }
  b -= B_W2;
  if (b < B_BND) {                       // ---- graph bounds (batch sorted) ----
    int n = b * 256 + tid;
    if (n >= N_NODES) return;
    int bb = a.batch[n];
    if (n == 0) gs[bb] = 0;
    else {
      int bp = a.batch[n - 1];
      if (bp != bb) { gs[bb] = n; ge[bp] = n - 1; }
    }
    if (n == N_NODES - 1) ge[bb] = N_NODES - 1;
    return;
  }
  b -= B_BND;
  {                                      // ---- degree count ----
    int e = b * 256 + tid;
    if (e >= TOT_E) return;
    int dst = (e < N_EDGES) ? a.ei[N_EDGES + e] : (e - N_EDGES);
    atomicAdd(&cnt[dst], 1);
  }
}

// ---------------- GEMM 1 (MFMA): xb(N,64) @ Wt1^T -> xl1|xr1 (N,256 each) ----------------
__global__ __launch_bounds__(256) void gemm1_mfma_k(
    const bf16* __restrict__ xb, const bf16* __restrict__ wt1,
    const float* __restrict__ par,
    bf16* __restrict__ xl1, bf16* __restrict__ xr1) {
  const int w = threadIdx.x >> 6, lane = threadIdx.x & 63;
  const int m0 = blockIdx.x * 32 + (w & 1) * 16;
  const int colbase = (w >> 1) * 256;
  const int lm = lane & 15, lk = lane >> 4;

  int arow = m0 + lm; if (arow >= N_NODES) arow = N_NODES - 1;
  const short8 a0 = *(const short8*)(xb + (size_t)arow * 64 + lk * 8);
  const short8 a1 = *(const short8*)(xb + (size_t)arow * 64 + 32 + lk * 8);

  f32x4 acc[16];
  const f32x4 z = {0.f, 0.f, 0.f, 0.f};
#pragma unroll
  for (int nt = 0; nt < 16; nt++) acc[nt] = z;

#pragma unroll
  for (int nt = 0; nt < 16; nt++) {
    int n = colbase + nt * 16 + lm;
    short8 b0 = *(const short8*)(wt1 + (size_t)n * 64 + lk * 8);
    short8 b1 = *(const short8*)(wt1 + (size_t)n * 64 + 32 + lk * 8);
    acc[nt] = __builtin_amdgcn_mfma_f32_16x16x32_bf16(a0, b0, acc[nt], 0, 0, 0);
    acc[nt] = __builtin_amdgcn_mfma_f32_16x16x32_bf16(a1, b1, acc[nt], 0, 0, 0);
  }

  const int r0 = m0 + (lane >> 4) * 4;
#pragma unroll
  for (int nt = 0; nt < 16; nt++) {
    int col = colbase + nt * 16 + lm;
    bf16* dst = (col < F1) ? xl1 : xr1;
    int c = (col < F1) ? col : col - F1;
    float bv = (col < F1) ? par[P_BL1 + c] : par[P_BR1 + c];
#pragma unroll
    for (int reg = 0; reg < 4; reg++) {
      int row = r0 + reg;
      if (row < N_NODES)
        dst[(size_t)row * F1 + c] = (bf16)(acc[nt][reg] + bv);
    }
  }
}

// ---------------- GEMM 2 (MFMA): h(N,256) @ Wt2^T -> xl2|xr2 (N,128 each) ----------------
__global__ __launch_bounds__(256) void gemm2_mfma_k(
    const bf16* __restrict__ h, const bf16* __restrict__ wt2,
    const float* __restrict__ par,
    bf16* __restrict__ xl2, bf16* __restrict__ xr2) {
  const int w = threadIdx.x >> 6, lane = threadIdx.x & 63;
  const int m0 = blockIdx.x * 32 + (w & 1) * 16;
  const int colbase = (w >> 1) * 128;
  const int lm = lane & 15, lk = lane >> 4;

  int arow = m0 + lm; if (arow >= N_NODES) arow = N_NODES - 1;
  const bf16* hrow = h + (size_t)arow * F1 + lk * 8;

  f32x4 acc[8];
  const f32x4 z = {0.f, 0.f, 0.f, 0.f};
#pragma unroll
  for (int nt = 0; nt < 8; nt++) acc[nt] = z;

#pragma unroll
  for (int kk = 0; kk < 256; kk += 32) {
    short8 a = *(const short8*)(hrow + kk);
#pragma unroll
    for (int nt = 0; nt < 8; nt++) {
      int n = colbase + nt * 16 + lm;
      short8 b = *(const short8*)(wt2 + (size_t)n * 256 + kk + lk * 8);
      acc[nt] = __builtin_amdgcn_mfma_f32_16x16x32_bf16(a, b, acc[nt], 0, 0, 0);
    }
  }

  const int r0 = m0 + (lane >> 4) * 4;
#pragma unroll
  for (int nt = 0; nt < 8; nt++) {
    int col = colbase + nt * 16 + lm;
    bf16* dst = (col < F2) ? xl2 : xr2;
    int c = (col < F2) ? col : col - F2;
    float bv = (col < F2) ? par[P_BL2 + c] : par[P_BR2 + c];
#pragma unroll
    for (int reg = 0; reg < 4; reg++) {
      int row = r0 + reg;
      if (row < N_NODES)
        dst[(size_t)row * F2 + c] = (bf16)(acc[nt][reg] + bv);
    }
  }
}

// ---------------- CSR scan (3-phase, multi-block) + scatter ----------------
__global__ __launch_bounds__(1024) void scan_a(const int* __restrict__ cnt,
                                               int* __restrict__ offs,
                                               int* __restrict__ bsum) {
  __shared__ int wsum[16];
  const int t = threadIdx.x;
  const int lane = t & 63, w = t >> 6;
  int idx = blockIdx.x * 1024 + t;
  int v = (idx < N_NODES) ? cnt[idx] : 0;
  int s = v;
#pragma unroll
  for (int off = 1; off < 64; off <<= 1) {
    int u = __shfl_up(s, off, 64);
    if (lane >= off) s += u;
  }
  if (lane == 63) wsum[w] = s;
  __syncthreads();
  int prefix = 0;
  for (int i = 0; i < w; i++) prefix += wsum[i];
  if (idx < N_NODES) offs[idx] = prefix + s - v;   // exclusive within block
  if (t == 1023) bsum[blockIdx.x] = prefix + s;    // block total
}

__global__ void scan_b(const int* __restrict__ bsum, int* __restrict__ boff,
                       int* __restrict__ offs) {
  const int lane = threadIdx.x;   // 64 threads, SCAN_BLKS<=64 values
  int v = (lane < SCAN_BLKS) ? bsum[lane] : 0;
  int s = v;
#pragma unroll
  for (int off = 1; off < 64; off <<= 1) {
    int u = __shfl_up(s, off, 64);
    if (lane >= off) s += u;
  }
  if (lane < SCAN_BLKS) boff[lane] = s - v;
  if (lane == SCAN_BLKS - 1) offs[N_NODES] = s;   // grand total
}

__global__ void scan_c(const int* __restrict__ boff, int* __restrict__ offs,
                       int* __restrict__ cursor) {
  int idx = blockIdx.x * 256 + threadIdx.x;
  if (idx >= N_NODES) return;
  int o = offs[idx] + boff[idx >> 10];
  offs[idx] = o;
  cursor[idx] = o;
}

__global__ void scatter_k(const int* __restrict__ ei, int* __restrict__ cursor,
                          int* __restrict__ csr) {
  int e = blockIdx.x * 256 + threadIdx.x;
  if (e >= TOT_E) return;
  int src, dst;
  if (e < N_EDGES) { src = ei[e]; dst = ei[N_EDGES + e]; }
  else             { src = dst = e - N_EDGES; }
  int pos = atomicAdd(&cursor[dst], 1);
  csr[pos] = src;
}

// ---------------- layer-1 aggregation: one wave per dst, 4 edge-groups ----------------
// Wave: 4 groups x 16 lanes. Group g handles edge base+g; lane sl holds
// channels sl*16..sl*16+15 (2 x 16B loads). Head = sl>>2; per-head logit
// reduce = 2 shfl within the 4-lane head subgroup. 4 edges + 8 loads in
// flight per wave iteration (latency hiding).
__global__ __launch_bounds__(256, 4) void agg1_k(
    const bf16* __restrict__ xl1, const bf16* __restrict__ xr1,
    const float* __restrict__ par,
    const int* __restrict__ offs, const int* __restrict__ csr,
    bf16* __restrict__ hout) {
  const int dst = blockIdx.x * 4 + (threadIdx.x >> 6);
  if (dst >= N_NODES) return;
  const int lane = threadIdx.x & 63;
  const int g = lane >> 4;        // 4 edge groups
  const int sl = lane & 15;
  const int chb = sl * 16;

  f2 r2[8], a2[8];
  load8bf2(xr1 + (size_t)dst * F1 + chb, r2);
  load8bf2(xr1 + (size_t)dst * F1 + chb + 8, r2 + 4);
#pragma unroll
  for (int j = 0; j < 4; j++) {
    float4 av = *(const float4*)(par + P_ATT1 + chb + 4*j);
    a2[2*j].x = av.x; a2[2*j].y = av.y; a2[2*j+1].x = av.z; a2[2*j+1].y = av.w;
  }

  const int e0 = offs[dst], e1 = offs[dst + 1];
  const f2 zf2 = {0.f, 0.f};
  f2 acc2[8];
#pragma unroll
  for (int j = 0; j < 8; j++) acc2[j] = zf2;
  float denom = 0.f;

  for (int base = e0; base < e1; base += 4) {
    int e = base + g;
    f2 v2[8];
    float lt;
    if (e < e1) {
      int src = csr[e];
      load8bf2(xl1 + (size_t)src * F1 + chb, v2);
      load8bf2(xl1 + (size_t)src * F1 + chb + 8, v2 + 4);
      f2 lt2 = zf2;
#pragma unroll
      for (int j = 0; j < 8; j++)
        lt2 = lrelu2(v2[j] + r2[j]) * a2[j] + lt2;
      lt = lt2.x + lt2.y;
    } else {
#pragma unroll
      for (int j = 0; j < 8; j++) v2[j] = zf2;
      lt = -1e30f;
    }
    // per-head reduce over the 4-lane head subgroup
    lt += __shfl_xor(lt, 1, 64);
    lt += __shfl_xor(lt, 2, 64);
    float p = __expf(fminf(lt, 60.f));   // logits O(1); invalid group -> 0
    denom += p;
    f2 pv; pv.x = p; pv.y = p;
#pragma unroll
    for (int j = 0; j < 8; j++) acc2[j] = pv * v2[j] + acc2[j];
  }

  // combine the 4 edge groups (lanes ^16 / ^32 share channels & head)
#pragma unroll
  for (int m = 16; m <= 32; m <<= 1) {
    denom += __shfl_xor(denom, m, 64);
#pragma unroll
    for (int j = 0; j < 8; j++) {
      acc2[j].x += __shfl_xor(acc2[j].x, m, 64);
      acc2[j].y += __shfl_xor(acc2[j].y, m, 64);
    }
  }

  if (g == 0) {
    float inv = 1.f / (denom + EPS_A);
    __align__(16) bf16 ob[16];
#pragma unroll
    for (int j = 0; j < 8; j++) {
      float o0 = fmaxf(acc2[j].x * inv + par[P_BIAS1 + chb + 2*j],     0.f);
      float o1 = fmaxf(acc2[j].y * inv + par[P_BIAS1 + chb + 2*j + 1], 0.f);
      ob[2*j] = (bf16)o0; ob[2*j+1] = (bf16)o1;
    }
    *(uint4*)(hout + (size_t)dst * F1 + chb)     = *(uint4*)ob;
    *(uint4*)(hout + (size_t)dst * F1 + chb + 8) = *(uint4*)(ob + 8);
  }
}

// ---------------- layer-2 aggregation ----------------
__global__ __launch_bounds__(256, 4) void agg2_k(
    const bf16* __restrict__ xl2, const bf16* __restrict__ xr2,
    const float* __restrict__ par,
    const int* __restrict__ offs, const int* __restrict__ csr,
    bf16* __restrict__ h2) {
  const int dst = blockIdx.x * 4 + (threadIdx.x >> 6);
  if (dst >= N_NODES) return;
  const int lane = threadIdx.x & 63;
  const int g = lane >> 3;
  const int sl = lane & 7;
  const int chb = sl * 16;

  f2 r2[8], a2[8];
  load8bf2(xr2 + (size_t)dst * F2 + chb, r2);
  load8bf2(xr2 + (size_t)dst * F2 + chb + 8, r2 + 4);
#pragma unroll
  for (int j = 0; j < 4; j++) {
    float4 av = *(const float4*)(par + P_ATT2 + chb + 4*j);
    a2[2*j].x = av.x; a2[2*j].y = av.y; a2[2*j+1].x = av.z; a2[2*j+1].y = av.w;
  }

  const int e0 = offs[dst], e1 = offs[dst + 1];
  const f2 zf2 = {0.f, 0.f};
  f2 acc2[8];
#pragma unroll
  for (int j = 0; j < 8; j++) acc2[j] = zf2;
  float denom = 0.f;

  for (int base = e0; base < e1; base += 8) {
    int e = base + g;
    f2 v2[8];
    float lt;
    if (e < e1) {
      int src = csr[e];
      load8bf2(xl2 + (size_t)src * F2 + chb, v2);
      load8bf2(xl2 + (size_t)src * F2 + chb + 8, v2 + 4);
      f2 lt2 = zf2;
#pragma unroll
      for (int j = 0; j < 8; j++)
        lt2 = lrelu2(v2[j] + r2[j]) * a2[j] + lt2;
      lt = lt2.x + lt2.y;
    } else {
#pragma unroll
      for (int j = 0; j < 8; j++) v2[j] = zf2;
      lt = -1e30f;
    }
    lt += __shfl_xor(lt, 1, 64);
    lt += __shfl_xor(lt, 2, 64);
    lt += __shfl_xor(lt, 4, 64);
    float p = __expf(fminf(lt, 60.f));
    denom += p;
    f2 pv; pv.x = p; pv.y = p;
#pragma unroll
    for (int j = 0; j < 8; j++) acc2[j] = pv * v2[j] + acc2[j];
  }

#pragma unroll
  for (int m = 8; m <= 32; m <<= 1) {
    denom += __shfl_xor(denom, m, 64);
#pragma unroll
    for (int j = 0; j < 8; j++) {
      acc2[j].x += __shfl_xor(acc2[j].x, m, 64);
      acc2[j].y += __shfl_xor(acc2[j].y, m, 64);
    }
  }

  if (g == 0) {
    float inv = 1.f / (denom + EPS_A);
    __align__(16) bf16 ob[16];
#pragma unroll
    for (int j = 0; j < 8; j++) {
      float o0 = fmaxf(acc2[j].x * inv + par[P_BIAS2 + chb + 2*j],     0.f);
      float o1 = fmaxf(acc2[j].y * inv + par[P_BIAS2 + chb + 2*j + 1], 0.f);
      ob[2*j] = (bf16)o0; ob[2*j+1] = (bf16)o1;
    }
    *(uint4*)(h2 + (size_t)dst * F2 + chb)     = *(uint4*)ob;
    *(uint4*)(h2 + (size_t)dst * F2 + chb + 8) = *(uint4*)(ob + 8);
  }
}

// ---------------- pooling ----------------
__global__ __launch_bounds__(256) void pool_k(
    const bf16* __restrict__ h2, const int* __restrict__ gs,
    const int* __restrict__ ge, const void* __restrict__ x,
    void* __restrict__ out) {
  const int flag = detect_f32_wave(x);
  const int g = blockIdx.x;
  const int t = threadIdx.x;
  const int c = t & 127, half = t >> 7;
  int s = gs[g], e = ge[g];
  if (s < 0 || e < s) { s = 0; e = -1; }   // empty graph (memset-init) -> 0
  float sum = 0.f;
  for (int n = s + half; n <= e; n += 2)
    sum += (float)h2[(size_t)n * F2 + c];
  __shared__ float red[128];
  if (half == 1) red[c] = sum;
  __syncthreads();
  if (half == 0) {
    float tot = sum + red[c];
    float cnt = (e >= s) ? (float)(e - s + 1) : 1.f;
    float v = tot / cnt;
    if (flag) ((float*)out)[g * F2 + c] = v;
    else      ((bf16*)out)[g * F2 + c] = (bf16)v;
  }
}

// ---------------- launch ----------------
extern "C" void kernel_launch(void* const* d_in, const int* in_sizes, int n_in,
                              void* d_out, int out_size, void* d_ws, size_t ws_size,
                              hipStream_t stream) {
  (void)in_sizes; (void)n_in; (void)out_size; (void)ws_size;
  const void* x     = d_in[0];
  const int*  ei    = (const int*)d_in[1];
  const int*  batch = (const int*)d_in[2];

  char* ws = (char*)d_ws;
  float* par  = (float*)(ws + OFF_PAR);
  bf16* xl1 = (bf16*)(ws + OFF_XL1);
  bf16* xr1 = (bf16*)(ws + OFF_XR1);
  bf16* h   = (bf16*)(ws + OFF_H);
  bf16* xl2 = (bf16*)(ws + OFF_XL2);
  bf16* xr2 = (bf16*)(ws + OFF_XR2);
  bf16* h2  = (bf16*)(ws + OFF_H2);
  bf16* xb  = (bf16*)(ws + OFF_XB);
  bf16* wt1 = (bf16*)(ws + OFF_WT1);
  bf16* wt2 = (bf16*)(ws + OFF_WT2);
  int* cnt    = (int*)(ws + OFF_CNT);
  int* offs   = (int*)(ws + OFF_OFFS);
  int* cursor = (int*)(ws + OFF_CUR);
  int* csr    = (int*)(ws + OFF_CSR);
  int* gs     = (int*)(ws + OFF_GS);
  int* ge     = (int*)(ws + OFF_GE);
  int* bsum   = (int*)(ws + OFF_BS);
  int* boff   = (int*)(ws + OFF_BO);

  hipMemsetAsync(cnt, 0, (size_t)N_NODES * 4, stream);
  hipMemsetAsync(gs, 0xFF, (size_t)(OFF_WT1 - OFF_GS), stream);  // gs/ge = -1

  PrepArgs pa;
  pa.x = x; pa.ei = ei; pa.batch = batch;
  for (int i = 0; i < 12; i++) pa.src[i] = d_in[3 + i];
  const int prep_blocks = B_CVT + B_XP + B_W1 + B_W2 + B_BND + B_CNT;
  prep_k<<<prep_blocks, 256, 0, stream>>>(pa, par, xb, wt1, wt2, gs, ge, cnt);

  scan_a<<<SCAN_BLKS, 1024, 0, stream>>>(cnt, offs, bsum);
  scan_b<<<1, 64, 0, stream>>>(bsum, boff, offs);
  scan_c<<<(N_NODES + 255) / 256, 256, 0, stream>>>(boff, offs, cursor);
  scatter_k<<<(TOT_E + 255) / 256, 256, 0, stream>>>(ei, cursor, csr);

  const int gblk = (N_NODES + 31) / 32;   // 1563
  gemm1_mfma_k<<<gblk, 256, 0, stream>>>(xb, wt1, par, xl1, xr1);
  agg1_k<<<(N_NODES + 3) / 4, 256, 0, stream>>>(xl1, xr1, par, offs, csr, h);
  gemm2_mfma_k<<<gblk, 256, 0, stream>>>(h, wt2, par, xl2, xr2);
  agg2_k<<<(N_NODES + 3) / 4, 256, 0, stream>>>(xl2, xr2, par, offs, csr, h2);
  pool_k<<<NGRAPH, 256, 0, stream>>>(h2, gs, ge, x, d_out);
}

// Round 9
// 493.242 us; speedup vs baseline: 1.2040x; 1.0552x over previous
//
#include <hip/hip_runtime.h>
#include <hip/hip_bf16.h>
#include <limits.h>

// ---------------- problem constants ----------------
#define N_NODES 50000
#define N_EDGES 800000
#define TOT_E   (N_EDGES + N_NODES)   // with self loops
#define IN_F    38
#define HIDC    64
#define NH      4
#define F1      256                    // NH*HIDC
#define F2      128                    // OUT
#define NGRAPH  128
#define NEG_SLOPE 0.2f
#define EPS_A   1e-16f

typedef __hip_bfloat16 bf16;
typedef __attribute__((ext_vector_type(8))) short short8;
typedef __attribute__((ext_vector_type(4))) float f32x4;
typedef __attribute__((ext_vector_type(2))) float f2;   // lowers to VOP3P v_pk_*_f32

// ---------------- ws layout ----------------
constexpr size_t al256(size_t x) { return (x + 255) & ~(size_t)255; }

// converted-params element offsets (f32 elements) — contiguous in this order
#define P_WL1   0
#define P_BL1   (P_WL1 + IN_F * F1)        // 9728
#define P_WR1   (P_BL1 + F1)               // 9984
#define P_BR1   (P_WR1 + IN_F * F1)        // 19712
#define P_ATT1  (P_BR1 + F1)               // 19968
#define P_BIAS1 (P_ATT1 + F1)              // 20224
#define P_WL2   (P_BIAS1 + F1)             // 20480
#define P_BL2   (P_WL2 + F1 * F2)          // 53248
#define P_WR2   (P_BL2 + F2)               // 53376
#define P_BR2   (P_WR2 + F1 * F2)          // 86144
#define P_ATT2  (P_BR2 + F2)               // 86272
#define P_BIAS2 (P_ATT2 + F2)              // 86400
#define P_TOTAL (P_BIAS2 + F2)             // 86528 = 338*256 exactly

constexpr size_t OFF_PAR  = 256;
constexpr size_t OFF_XL1  = OFF_PAR + al256((size_t)P_TOTAL * 4);   // reused as h2 later
constexpr size_t OFF_XR1  = OFF_XL1 + al256((size_t)N_NODES * F1 * 2);
constexpr size_t OFF_H    = OFF_XR1 + al256((size_t)N_NODES * F1 * 2);
constexpr size_t OFF_XL2  = OFF_H   + al256((size_t)N_NODES * F1 * 2);
constexpr size_t OFF_XR2  = OFF_XL2 + al256((size_t)N_NODES * F2 * 2);
constexpr size_t OFF_CNT  = OFF_XR2 + al256((size_t)N_NODES * F2 * 2);
constexpr size_t OFF_OFFS = OFF_CNT + al256((size_t)N_NODES * 4);
constexpr size_t OFF_CUR  = OFF_OFFS+ al256((size_t)(N_NODES + 1) * 4);
constexpr size_t OFF_CSR  = OFF_CUR + al256((size_t)(N_NODES + 1) * 4);
constexpr size_t OFF_GS   = OFF_CSR + al256((size_t)TOT_E * 4);
constexpr size_t OFF_GE   = OFF_GS  + al256((size_t)NGRAPH * 4);    // adjacent to GS
constexpr size_t OFF_WT1  = OFF_GE  + al256((size_t)NGRAPH * 4);    // 512x64 bf16
constexpr size_t OFF_WT2  = OFF_WT1 + al256((size_t)512 * 64 * 2);  // 256x256 bf16
constexpr size_t OFF_BS   = OFF_WT2 + al256((size_t)256 * 256 * 2); // 49 block sums
constexpr size_t OFF_BO   = OFF_BS  + al256(64 * 4);                // 49 block offsets
constexpr size_t OFF_H2   = OFF_XL1;  // xl1 dead after agg1
constexpr size_t OFF_XB   = OFF_H;    // xb (N x 64 bf16) dead before agg1 writes h

#define SCAN_BLKS 49   // ceil(50000/1024)

// ---------------- helpers ----------------
// uint4 (8 bf16) -> 4 x f2; pairs are (ch 2i, ch 2i+1)
__device__ __forceinline__ void unpack8bf2(uint4 q, f2* f) {
  unsigned v[4] = {q.x, q.y, q.z, q.w};
#pragma unroll
  for (int i = 0; i < 4; i++) {
    f2 t;
    t.x = __uint_as_float(v[i] << 16);
    t.y = __uint_as_float(v[i] & 0xffff0000u);
    f[i] = t;
  }
}

__device__ __forceinline__ void load8bf2(const bf16* __restrict__ p, f2* f) {
  unpack8bf2(*(const uint4*)p, f);
}

// leaky_relu(s) = 0.6*s + 0.4*|s|
__device__ __forceinline__ f2 lrelu2(f2 s) {
  f2 as;
  as.x = __uint_as_float(__float_as_uint(s.x) & 0x7fffffffu);
  as.y = __uint_as_float(__float_as_uint(s.y) & 0x7fffffffu);
  return 0.6f * s + 0.4f * as;
}

// wave-cooperative dtype sniff: 1 = inputs are f32, 0 = bf16.
__device__ __forceinline__ int detect_f32_wave(const void* __restrict__ x) {
  const unsigned short* u = (const unsigned short*)x;
  unsigned short b = u[threadIdx.x & 63];
  int e = (b >> 7) & 0xFF;
  unsigned long long m = __ballot(!((e == 0) || (e >= 96 && e <= 158)));
  return __popcll(m) > 8;
}

// ---------------- fused prep kernel ----------------
#define B_CVT  338
#define B_XP   12500
#define B_W1   128
#define B_W2   256
#define B_BND  196
#define B_CNT  3321

struct PrepArgs {
  const void* x;
  const void* src[12];     // Wl1,bl1,Wr1,br1,att1,bias1,Wl2,bl2,Wr2,br2,att2,bias2
  const int* ei;
  const int* batch;
};

__global__ __launch_bounds__(256) void prep_k(
    PrepArgs a, float* __restrict__ par, bf16* __restrict__ xb,
    bf16* __restrict__ wt1, bf16* __restrict__ wt2,
    int* __restrict__ gs, int* __restrict__ ge, int* __restrict__ cnt) {
  int b = blockIdx.x;
  const int tid = threadIdx.x;

  if (b < B_CVT) {                       // ---- param convert -> f32 ----
    const int flag = detect_f32_wave(a.x);
    int idx = b * 256 + tid;             // [0, P_TOTAL)
    const void* p; int base;
    if      (idx < P_BL1)  { p = a.src[0];  base = P_WL1; }
    else if (idx < P_WR1)  { p = a.src[1];  base = P_BL1; }
    else if (idx < P_BR1)  { p = a.src[2];  base = P_WR1; }
    else if (idx < P_ATT1) { p = a.src[3];  base = P_BR1; }
    else if (idx < P_BIAS1){ p = a.src[4];  base = P_ATT1; }
    else if (idx < P_WL2)  { p = a.src[5];  base = P_BIAS1; }
    else if (idx < P_BL2)  { p = a.src[6];  base = P_WL2; }
    else if (idx < P_WR2)  { p = a.src[7];  base = P_BL2; }
    else if (idx < P_BR2)  { p = a.src[8];  base = P_WR2; }
    else if (idx < P_ATT2) { p = a.src[9];  base = P_BR2; }
    else if (idx < P_BIAS2){ p = a.src[10]; base = P_ATT2; }
    else                   { p = a.src[11]; base = P_BIAS2; }
    int li = idx - base;
    par[idx] = flag ? ((const float*)p)[li] : (float)((const bf16*)p)[li];
    return;
  }
  b -= B_CVT;
  if (b < B_XP) {                        // ---- x -> xb (N x 64, zero-pad K) ----
    const int flag = detect_f32_wave(a.x);
    int i = b * 256 + tid;               // n*64 + k
    int n = i >> 6, k = i & 63;
    float v = 0.f;
    if (k < IN_F) {
      int idx = n * IN_F + k;
      v = flag ? ((const float*)a.x)[idx] : (float)((const bf16*)a.x)[idx];
    }
    xb[i] = (bf16)v;
    return;
  }
  b -= B_XP;
  if (b < B_W1) {                        // ---- Wt1[n][k] 512x64 ----
    const int flag = detect_f32_wave(a.x);
    int i = b * 256 + tid;
    int n = i >> 6, k = i & 63;
    float v = 0.f;
    if (k < IN_F) {
      const void* W = (n < F1) ? a.src[0] : a.src[2];
      int col = (n < F1) ? n : n - F1;
      int idx = k * F1 + col;
      v = flag ? ((const float*)W)[idx] : (float)((const bf16*)W)[idx];
    }
    wt1[i] = (bf16)v;
    return;
  }
  b -= B_W1;
  if (b < B_W2) {                        // ---- Wt2[n][k] 256x256 ----
    const int flag = detect_f32_wave(a.x);
    int i = b * 256 + tid;
    int n = i >> 8, k = i & 255;
    const void* W = (n < F2) ? a.src[6] : a.src[8];
    int col = (n < F2) ? n : n - F2;
    int idx = k * F2 + col;
    float v = flag ? ((const float*)W)[idx] : (float)((const bf16*)W)[idx];
    wt2[i] = (bf16)v;
    return;
  }
  b -= B_W2;
  if (b < B_BND) {                       // ---- graph bounds (batch sorted) ----
    int n = b * 256 + tid;
    if (n >= N_NODES) return;
    int bb = a.batch[n];
    if (n == 0) gs[bb] = 0;
    else {
      int bp = a.batch[n - 1];
      if (bp != bb) { gs[bb] = n; ge[bp] = n - 1; }
    }
    if (n == N_NODES - 1) ge[bb] = N_NODES - 1;
    return;
  }
  b -= B_BND;
  {                                      // ---- degree count ----
    int e = b * 256 + tid;
    if (e >= TOT_E) return;
    int dst = (e < N_EDGES) ? a.ei[N_EDGES + e] : (e - N_EDGES);
    atomicAdd(&cnt[dst], 1);
  }
}

// ---------------- GEMM 1 (MFMA): xb(N,64) @ Wt1^T -> xl1|xr1 (N,256 each) ----------------
__global__ __launch_bounds__(256) void gemm1_mfma_k(
    const bf16* __restrict__ xb, const bf16* __restrict__ wt1,
    const float* __restrict__ par,
    bf16* __restrict__ xl1, bf16* __restrict__ xr1) {
  const int w = threadIdx.x >> 6, lane = threadIdx.x & 63;
  const int m0 = blockIdx.x * 32 + (w & 1) * 16;
  const int colbase = (w >> 1) * 256;
  const int lm = lane & 15, lk = lane >> 4;

  int arow = m0 + lm; if (arow >= N_NODES) arow = N_NODES - 1;
  const short8 a0 = *(const short8*)(xb + (size_t)arow * 64 + lk * 8);
  const short8 a1 = *(const short8*)(xb + (size_t)arow * 64 + 32 + lk * 8);

  f32x4 acc[16];
  const f32x4 z = {0.f, 0.f, 0.f, 0.f};
#pragma unroll
  for (int nt = 0; nt < 16; nt++) acc[nt] = z;

#pragma unroll
  for (int nt = 0; nt < 16; nt++) {
    int n = colbase + nt * 16 + lm;
    short8 b0 = *(const short8*)(wt1 + (size_t)n * 64 + lk * 8);
    short8 b1 = *(const short8*)(wt1 + (size_t)n * 64 + 32 + lk * 8);
    acc[nt] = __builtin_amdgcn_mfma_f32_16x16x32_bf16(a0, b0, acc[nt], 0, 0, 0);
    acc[nt] = __builtin_amdgcn_mfma_f32_16x16x32_bf16(a1, b1, acc[nt], 0, 0, 0);
  }

  const int r0 = m0 + (lane >> 4) * 4;
#pragma unroll
  for (int nt = 0; nt < 16; nt++) {
    int col = colbase + nt * 16 + lm;
    bf16* dst = (col < F1) ? xl1 : xr1;
    int c = (col < F1) ? col : col - F1;
    float bv = (col < F1) ? par[P_BL1 + c] : par[P_BR1 + c];
#pragma unroll
    for (int reg = 0; reg < 4; reg++) {
      int row = r0 + reg;
      if (row < N_NODES)
        dst[(size_t)row * F1 + c] = (bf16)(acc[nt][reg] + bv);
    }
  }
}

// ---------------- GEMM 2 (MFMA): h(N,256) @ Wt2^T -> xl2|xr2 (N,128 each) ----------------
__global__ __launch_bounds__(256) void gemm2_mfma_k(
    const bf16* __restrict__ h, const bf16* __restrict__ wt2,
    const float* __restrict__ par,
    bf16* __restrict__ xl2, bf16* __restrict__ xr2) {
  const int w = threadIdx.x >> 6, lane = threadIdx.x & 63;
  const int m0 = blockIdx.x * 32 + (w & 1) * 16;
  const int colbase = (w >> 1) * 128;
  const int lm = lane & 15, lk = lane >> 4;

  int arow = m0 + lm; if (arow >= N_NODES) arow = N_NODES - 1;
  const bf16* hrow = h + (size_t)arow * F1 + lk * 8;

  f32x4 acc[8];
  const f32x4 z = {0.f, 0.f, 0.f, 0.f};
#pragma unroll
  for (int nt = 0; nt < 8; nt++) acc[nt] = z;

#pragma unroll
  for (int kk = 0; kk < 256; kk += 32) {
    short8 a = *(const short8*)(hrow + kk);
#pragma unroll
    for (int nt = 0; nt < 8; nt++) {
      int n = colbase + nt * 16 + lm;
      short8 b = *(const short8*)(wt2 + (size_t)n * 256 + kk + lk * 8);
      acc[nt] = __builtin_amdgcn_mfma_f32_16x16x32_bf16(a, b, acc[nt], 0, 0, 0);
    }
  }

  const int r0 = m0 + (lane >> 4) * 4;
#pragma unroll
  for (int nt = 0; nt < 8; nt++) {
    int col = colbase + nt * 16 + lm;
    bf16* dst = (col < F2) ? xl2 : xr2;
    int c = (col < F2) ? col : col - F2;
    float bv = (col < F2) ? par[P_BL2 + c] : par[P_BR2 + c];
#pragma unroll
    for (int reg = 0; reg < 4; reg++) {
      int row = r0 + reg;
      if (row < N_NODES)
        dst[(size_t)row * F2 + c] = (bf16)(acc[nt][reg] + bv);
    }
  }
}

// ---------------- CSR scan (3-phase, multi-block) + scatter ----------------
__global__ __launch_bounds__(1024) void scan_a(const int* __restrict__ cnt,
                                               int* __restrict__ offs,
                                               int* __restrict__ bsum) {
  __shared__ int wsum[16];
  const int t = threadIdx.x;
  const int lane = t & 63, w = t >> 6;
  int idx = blockIdx.x * 1024 + t;
  int v = (idx < N_NODES) ? cnt[idx] : 0;
  int s = v;
#pragma unroll
  for (int off = 1; off < 64; off <<= 1) {
    int u = __shfl_up(s, off, 64);
    if (lane >= off) s += u;
  }
  if (lane == 63) wsum[w] = s;
  __syncthreads();
  int prefix = 0;
  for (int i = 0; i < w; i++) prefix += wsum[i];
  if (idx < N_NODES) offs[idx] = prefix + s - v;   // exclusive within block
  if (t == 1023) bsum[blockIdx.x] = prefix + s;    // block total
}

__global__ void scan_b(const int* __restrict__ bsum, int* __restrict__ boff,
                       int* __restrict__ offs) {
  const int lane = threadIdx.x;   // 64 threads, SCAN_BLKS<=64 values
  int v = (lane < SCAN_BLKS) ? bsum[lane] : 0;
  int s = v;
#pragma unroll
  for (int off = 1; off < 64; off <<= 1) {
    int u = __shfl_up(s, off, 64);
    if (lane >= off) s += u;
  }
  if (lane < SCAN_BLKS) boff[lane] = s - v;
  if (lane == SCAN_BLKS - 1) offs[N_NODES] = s;   // grand total
}

__global__ void scan_c(const int* __restrict__ boff, int* __restrict__ offs,
                       int* __restrict__ cursor) {
  int idx = blockIdx.x * 256 + threadIdx.x;
  if (idx >= N_NODES) return;
  int o = offs[idx] + boff[idx >> 10];
  offs[idx] = o;
  cursor[idx] = o;
}

__global__ void scatter_k(const int* __restrict__ ei, int* __restrict__ cursor,
                          int* __restrict__ csr) {
  int e = blockIdx.x * 256 + threadIdx.x;
  if (e >= TOT_E) return;
  int src, dst;
  if (e < N_EDGES) { src = ei[e]; dst = ei[N_EDGES + e]; }
  else             { src = dst = e - N_EDGES; }
  int pos = atomicAdd(&cursor[dst], 1);
  csr[pos] = src;
}

// ---------------- layer-1 aggregation: one wave per dst, 2 groups x 32 lanes,
// register double-buffer prefetch of the next edge's row ----------------
__global__ __launch_bounds__(256, 4) void agg1_k(
    const bf16* __restrict__ xl1, const bf16* __restrict__ xr1,
    const float* __restrict__ par,
    const int* __restrict__ offs, const int* __restrict__ csr,
    bf16* __restrict__ hout) {
  const int dst = blockIdx.x * 4 + (threadIdx.x >> 6);
  if (dst >= N_NODES) return;
  const int lane = threadIdx.x & 63;
  const int g = lane >> 5;        // 2 edge groups
  const int sl = lane & 31;
  const int chb = sl * 8;

  f2 r2[4], a2[4];
  load8bf2(xr1 + (size_t)dst * F1 + chb, r2);
  {
    float4 aa = *(const float4*)(par + P_ATT1 + chb);
    float4 ab = *(const float4*)(par + P_ATT1 + chb + 4);
    a2[0].x = aa.x; a2[0].y = aa.y; a2[1].x = aa.z; a2[1].y = aa.w;
    a2[2].x = ab.x; a2[2].y = ab.y; a2[3].x = ab.z; a2[3].y = ab.w;
  }

  const int e0 = offs[dst], e1 = offs[dst + 1];
  const f2 zf2 = {0.f, 0.f};
  f2 acc2[4];
#pragma unroll
  for (int j = 0; j < 4; j++) acc2[j] = zf2;
  float denom = 0.f;

  // prime the pipeline: edge e0+g
  int e = e0 + g;
  const uint4 zq = {0, 0, 0, 0};
  bool valid = e < e1;
  uint4 q = valid ? *(const uint4*)(xl1 + (size_t)csr[e] * F1 + chb) : zq;

  for (int base = e0; base < e1; base += 2) {
    const uint4 qc = q;
    const bool vc = valid;
    // prefetch next edge's row before touching qc
    e += 2;
    valid = e < e1;
    q = valid ? *(const uint4*)(xl1 + (size_t)csr[e] * F1 + chb) : zq;

    f2 v2[4];
    unpack8bf2(qc, v2);     // invalid -> zeros
    f2 lt2 = zf2;
#pragma unroll
    for (int j = 0; j < 4; j++)
      lt2 = lrelu2(v2[j] + r2[j]) * a2[j] + lt2;
    float lt = vc ? (lt2.x + lt2.y) : -1e30f;
    // per-head reduce over this lane's 8-lane head subgroup
    lt += __shfl_xor(lt, 1, 64);
    lt += __shfl_xor(lt, 2, 64);
    lt += __shfl_xor(lt, 4, 64);
    float p = __expf(fminf(lt, 60.f));   // logits O(1); invalid group -> 0
    denom += p;
    f2 pv; pv.x = p; pv.y = p;
#pragma unroll
    for (int j = 0; j < 4; j++) acc2[j] = pv * v2[j] + acc2[j];
  }

  // combine the 2 edge groups (lane ^ 32 has same channels & head)
  denom += __shfl_xor(denom, 32, 64);
#pragma unroll
  for (int j = 0; j < 4; j++) {
    acc2[j].x += __shfl_xor(acc2[j].x, 32, 64);
    acc2[j].y += __shfl_xor(acc2[j].y, 32, 64);
  }

  if (g == 0) {
    float inv = 1.f / (denom + EPS_A);
    __align__(16) bf16 ob[8];
#pragma unroll
    for (int j = 0; j < 4; j++) {
      float o0 = fmaxf(acc2[j].x * inv + par[P_BIAS1 + chb + 2*j],     0.f);
      float o1 = fmaxf(acc2[j].y * inv + par[P_BIAS1 + chb + 2*j + 1], 0.f);
      ob[2*j] = (bf16)o0; ob[2*j+1] = (bf16)o1;
    }
    *(uint4*)(hout + (size_t)dst * F1 + chb) = *(uint4*)ob;
  }
}

// ---------------- layer-2 aggregation: 8 groups x 8 lanes + prefetch ----------------
__global__ __launch_bounds__(256, 4) void agg2_k(
    const bf16* __restrict__ xl2, const bf16* __restrict__ xr2,
    const float* __restrict__ par,
    const int* __restrict__ offs, const int* __restrict__ csr,
    bf16* __restrict__ h2) {
  const int dst = blockIdx.x * 4 + (threadIdx.x >> 6);
  if (dst >= N_NODES) return;
  const int lane = threadIdx.x & 63;
  const int g = lane >> 3;
  const int sl = lane & 7;
  const int chb = sl * 16;

  f2 r2[8], a2[8];
  load8bf2(xr2 + (size_t)dst * F2 + chb, r2);
  load8bf2(xr2 + (size_t)dst * F2 + chb + 8, r2 + 4);
#pragma unroll
  for (int j = 0; j < 4; j++) {
    float4 av = *(const float4*)(par + P_ATT2 + chb + 4*j);
    a2[2*j].x = av.x; a2[2*j].y = av.y; a2[2*j+1].x = av.z; a2[2*j+1].y = av.w;
  }

  const int e0 = offs[dst], e1 = offs[dst + 1];
  const f2 zf2 = {0.f, 0.f};
  f2 acc2[8];
#pragma unroll
  for (int j = 0; j < 8; j++) acc2[j] = zf2;
  float denom = 0.f;

  const uint4 zq = {0, 0, 0, 0};
  int e = e0 + g;
  bool valid = e < e1;
  uint4 qa = zq, qb = zq;
  if (valid) {
    const bf16* p = xl2 + (size_t)csr[e] * F2 + chb;
    qa = *(const uint4*)p;
    qb = *(const uint4*)(p + 8);
  }

  for (int base = e0; base < e1; base += 8) {
    const uint4 qac = qa, qbc = qb;
    const bool vc = valid;
    e += 8;
    valid = e < e1;
    if (valid) {
      const bf16* p = xl2 + (size_t)csr[e] * F2 + chb;
      qa = *(const uint4*)p;
      qb = *(const uint4*)(p + 8);
    } else { qa = zq; qb = zq; }

    f2 v2[8];
    unpack8bf2(qac, v2);
    unpack8bf2(qbc, v2 + 4);
    f2 lt2 = zf2;
#pragma unroll
    for (int j = 0; j < 8; j++)
      lt2 = lrelu2(v2[j] + r2[j]) * a2[j] + lt2;
    float lt = vc ? (lt2.x + lt2.y) : -1e30f;
    lt += __shfl_xor(lt, 1, 64);
    lt += __shfl_xor(lt, 2, 64);
    lt += __shfl_xor(lt, 4, 64);
    float p = __expf(fminf(lt, 60.f));
    denom += p;
    f2 pv; pv.x = p; pv.y = p;
#pragma unroll
    for (int j = 0; j < 8; j++) acc2[j] = pv * v2[j] + acc2[j];
  }

#pragma unroll
  for (int m = 8; m <= 32; m <<= 1) {
    denom += __shfl_xor(denom, m, 64);
#pragma unroll
    for (int j = 0; j < 8; j++) {
      acc2[j].x += __shfl_xor(acc2[j].x, m, 64);
      acc2[j].y += __shfl_xor(acc2[j].y, m, 64);
    }
  }

  if (g == 0) {
    float inv = 1.f / (denom + EPS_A);
    __align__(16) bf16 ob[16];
#pragma unroll
    for (int j = 0; j < 8; j++) {
      float o0 = fmaxf(acc2[j].x * inv + par[P_BIAS2 + chb + 2*j],     0.f);
      float o1 = fmaxf(acc2[j].y * inv + par[P_BIAS2 + chb + 2*j + 1], 0.f);
      ob[2*j] = (bf16)o0; ob[2*j+1] = (bf16)o1;
    }
    *(uint4*)(h2 + (size_t)dst * F2 + chb)     = *(uint4*)ob;
    *(uint4*)(h2 + (size_t)dst * F2 + chb + 8) = *(uint4*)(ob + 8);
  }
}

// ---------------- pooling ----------------
__global__ __launch_bounds__(256) void pool_k(
    const bf16* __restrict__ h2, const int* __restrict__ gs,
    const int* __restrict__ ge, const void* __restrict__ x,
    void* __restrict__ out) {
  const int flag = detect_f32_wave(x);
  const int g = blockIdx.x;
  const int t = threadIdx.x;
  const int c = t & 127, half = t >> 7;
  int s = gs[g], e = ge[g];
  if (s < 0 || e < s) { s = 0; e = -1; }   // empty graph (memset-init) -> 0
  float sum = 0.f;
  for (int n = s + half; n <= e; n += 2)
    sum += (float)h2[(size_t)n * F2 + c];
  __shared__ float red[128];
  if (half == 1) red[c] = sum;
  __syncthreads();
  if (half == 0) {
    float tot = sum + red[c];
    float cnt = (e >= s) ? (float)(e - s + 1) : 1.f;
    float v = tot / cnt;
    if (flag) ((float*)out)[g * F2 + c] = v;
    else      ((bf16*)out)[g * F2 + c] = (bf16)v;
  }
}

// ---------------- launch ----------------
extern "C" void kernel_launch(void* const* d_in, const int* in_sizes, int n_in,
                              void* d_out, int out_size, void* d_ws, size_t ws_size,
                              hipStream_t stream) {
  (void)in_sizes; (void)n_in; (void)out_size; (void)ws_size;
  const void* x     = d_in[0];
  const int*  ei    = (const int*)d_in[1];
  const int*  batch = (const int*)d_in[2];

  char* ws = (char*)d_ws;
  float* par  = (float*)(ws + OFF_PAR);
  bf16* xl1 = (bf16*)(ws + OFF_XL1);
  bf16* xr1 = (bf16*)(ws + OFF_XR1);
  bf16* h   = (bf16*)(ws + OFF_H);
  bf16* xl2 = (bf16*)(ws + OFF_XL2);
  bf16* xr2 = (bf16*)(ws + OFF_XR2);
  bf16* h2  = (bf16*)(ws + OFF_H2);
  bf16* xb  = (bf16*)(ws + OFF_XB);
  bf16* wt1 = (bf16*)(ws + OFF_WT1);
  bf16* wt2 = (bf16*)(ws + OFF_WT2);
  int* cnt    = (int*)(ws + OFF_CNT);
  int* offs   = (int*)(ws + OFF_OFFS);
  int* cursor = (int*)(ws + OFF_CUR);
  int* csr    = (int*)(ws + OFF_CSR);
  int* gs     = (int*)(ws + OFF_GS);
  int* ge     = (int*)(ws + OFF_GE);
  int* bsum   = (int*)(ws + OFF_BS);
  int* boff   = (int*)(ws + OFF_BO);

  hipMemsetAsync(cnt, 0, (size_t)N_NODES * 4, stream);
  hipMemsetAsync(gs, 0xFF, (size_t)(OFF_WT1 - OFF_GS), stream);  // gs/ge = -1

  PrepArgs pa;
  pa.x = x; pa.ei = ei; pa.batch = batch;
  for (int i = 0; i < 12; i++) pa.src[i] = d_in[3 + i];
  const int prep_blocks = B_CVT + B_XP + B_W1 + B_W2 + B_BND + B_CNT;
  prep_k<<<prep_blocks, 256, 0, stream>>>(pa, par, xb, wt1, wt2, gs, ge, cnt);

  scan_a<<<SCAN_BLKS, 1024, 0, stream>>>(cnt, offs, bsum);
  scan_b<<<1, 64, 0, stream>>>(bsum, boff, offs);
  scan_c<<<(N_NODES + 255) / 256, 256, 0, stream>>>(boff, offs, cursor);
  scatter_k<<<(TOT_E + 255) / 256, 256, 0, stream>>>(ei, cursor, csr);

  const int gblk = (N_NODES + 31) / 32;   // 1563
  gemm1_mfma_k<<<gblk, 256, 0, stream>>>(xb, wt1, par, xl1, xr1);
  agg1_k<<<(N_NODES + 3) / 4, 256, 0, stream>>>(xl1, xr1, par, offs, csr, h);
  gemm2_mfma_k<<<gblk, 256, 0, stream>>>(h, wt2, par, xl2, xr2);
  agg2_k<<<(N_NODES + 3) / 4, 256, 0, stream>>>(xl2, xr2, par, offs, csr, h2);
  pool_k<<<NGRAPH, 256, 0, stream>>>(h2, gs, ge, x, d_out);
}

// Round 10
// 464.395 us; speedup vs baseline: 1.2788x; 1.0621x over previous
//
#include <hip/hip_runtime.h>
#include <hip/hip_bf16.h>
#include <limits.h>

// ---------------- problem constants ----------------
#define N_NODES 50000
#define N_EDGES 800000
#define TOT_E   (N_EDGES + N_NODES)   // with self loops
#define IN_F    38
#define HIDC    64
#define NH      4
#define F1      256                    // NH*HIDC
#define F2      128                    // OUT
#define NGRAPH  128
#define NEG_SLOPE 0.2f
#define EPS_A   1e-16f

typedef __hip_bfloat16 bf16;
typedef __attribute__((ext_vector_type(8))) short short8;
typedef __attribute__((ext_vector_type(4))) float f32x4;
typedef __attribute__((ext_vector_type(2))) float f2;   // lowers to VOP3P v_pk_*_f32

// ---------------- ws layout ----------------
constexpr size_t al256(size_t x) { return (x + 255) & ~(size_t)255; }

// converted-params element offsets (f32 elements) — contiguous in this order
#define P_WL1   0
#define P_BL1   (P_WL1 + IN_F * F1)        // 9728
#define P_WR1   (P_BL1 + F1)               // 9984
#define P_BR1   (P_WR1 + IN_F * F1)        // 19712
#define P_ATT1  (P_BR1 + F1)               // 19968
#define P_BIAS1 (P_ATT1 + F1)              // 20224
#define P_WL2   (P_BIAS1 + F1)             // 20480
#define P_BL2   (P_WL2 + F1 * F2)          // 53248
#define P_WR2   (P_BL2 + F2)               // 53376
#define P_BR2   (P_WR2 + F1 * F2)          // 86144
#define P_ATT2  (P_BR2 + F2)               // 86272
#define P_BIAS2 (P_ATT2 + F2)              // 86400
#define P_TOTAL (P_BIAS2 + F2)             // 86528 = 338*256 exactly

constexpr size_t OFF_PAR  = 256;
constexpr size_t OFF_XL1  = OFF_PAR + al256((size_t)P_TOTAL * 4);   // reused as h2 later
constexpr size_t OFF_XR1  = OFF_XL1 + al256((size_t)N_NODES * F1 * 2);
constexpr size_t OFF_H    = OFF_XR1 + al256((size_t)N_NODES * F1 * 2);
constexpr size_t OFF_XL2  = OFF_H   + al256((size_t)N_NODES * F1 * 2);
constexpr size_t OFF_XR2  = OFF_XL2 + al256((size_t)N_NODES * F2 * 2);
constexpr size_t OFF_CNT  = OFF_XR2 + al256((size_t)N_NODES * F2 * 2);
constexpr size_t OFF_OFFS = OFF_CNT + al256((size_t)N_NODES * 4);
constexpr size_t OFF_CUR  = OFF_OFFS+ al256((size_t)(N_NODES + 1) * 4);
constexpr size_t OFF_CSR  = OFF_CUR + al256((size_t)(N_NODES + 1) * 4);
constexpr size_t OFF_GS   = OFF_CSR + al256((size_t)TOT_E * 4);
constexpr size_t OFF_GE   = OFF_GS  + al256((size_t)NGRAPH * 4);    // adjacent to GS
constexpr size_t OFF_WT1  = OFF_GE  + al256((size_t)NGRAPH * 4);    // 512x64 bf16
constexpr size_t OFF_WT2  = OFF_WT1 + al256((size_t)512 * 64 * 2);  // 256x256 bf16
constexpr size_t OFF_BS   = OFF_WT2 + al256((size_t)256 * 256 * 2); // 49 block sums
constexpr size_t OFF_BO   = OFF_BS  + al256(64 * 4);                // 49 block offsets
constexpr size_t OFF_H2   = OFF_XL1;  // xl1 dead after agg1
constexpr size_t OFF_XB   = OFF_H;    // xb (N x 64 bf16) dead before agg1 writes h

#define SCAN_BLKS 49   // ceil(50000/1024)
#define GBLK 1563      // ceil(50000/32)  gemm row-blocks
#define EBL  3321      // ceil(TOT_E/256) scatter blocks

// ---------------- helpers ----------------
// uint4 (8 bf16) -> 4 x f2; pairs are (ch 2i, ch 2i+1)
__device__ __forceinline__ void unpack8bf2(uint4 q, f2* f) {
  unsigned v[4] = {q.x, q.y, q.z, q.w};
#pragma unroll
  for (int i = 0; i < 4; i++) {
    f2 t;
    t.x = __uint_as_float(v[i] << 16);
    t.y = __uint_as_float(v[i] & 0xffff0000u);
    f[i] = t;
  }
}

__device__ __forceinline__ void load8bf2(const bf16* __restrict__ p, f2* f) {
  unpack8bf2(*(const uint4*)p, f);
}

// leaky_relu(s) = 0.6*s + 0.4*|s|
__device__ __forceinline__ f2 lrelu2(f2 s) {
  f2 as;
  as.x = __uint_as_float(__float_as_uint(s.x) & 0x7fffffffu);
  as.y = __uint_as_float(__float_as_uint(s.y) & 0x7fffffffu);
  return 0.6f * s + 0.4f * as;
}

// wave-cooperative dtype sniff: 1 = inputs are f32, 0 = bf16.
__device__ __forceinline__ int detect_f32_wave(const void* __restrict__ x) {
  const unsigned short* u = (const unsigned short*)x;
  unsigned short b = u[threadIdx.x & 63];
  int e = (b >> 7) & 0xFF;
  unsigned long long m = __ballot(!((e == 0) || (e >= 96 && e <= 158)));
  return __popcll(m) > 8;
}

// ---------------- fused prep kernel ----------------
#define B_CVT  338
#define B_XP   12500
#define B_W1   128
#define B_W2   256
#define B_BND  196
#define B_CNT  3321

struct PrepArgs {
  const void* x;
  const void* src[12];     // Wl1,bl1,Wr1,br1,att1,bias1,Wl2,bl2,Wr2,br2,att2,bias2
  const int* ei;
  const int* batch;
};

__global__ __launch_bounds__(256) void prep_k(
    PrepArgs a, float* __restrict__ par, bf16* __restrict__ xb,
    bf16* __restrict__ wt1, bf16* __restrict__ wt2,
    int* __restrict__ gs, int* __restrict__ ge, int* __restrict__ cnt) {
  int b = blockIdx.x;
  const int tid = threadIdx.x;

  if (b < B_CVT) {                       // ---- param convert -> f32 ----
    const int flag = detect_f32_wave(a.x);
    int idx = b * 256 + tid;             // [0, P_TOTAL)
    const void* p; int base;
    if      (idx < P_BL1)  { p = a.src[0];  base = P_WL1; }
    else if (idx < P_WR1)  { p = a.src[1];  base = P_BL1; }
    else if (idx < P_BR1)  { p = a.src[2];  base = P_WR1; }
    else if (idx < P_ATT1) { p = a.src[3];  base = P_BR1; }
    else if (idx < P_BIAS1){ p = a.src[4];  base = P_ATT1; }
    else if (idx < P_WL2)  { p = a.src[5];  base = P_BIAS1; }
    else if (idx < P_BL2)  { p = a.src[6];  base = P_WL2; }
    else if (idx < P_WR2)  { p = a.src[7];  base = P_BL2; }
    else if (idx < P_BR2)  { p = a.src[8];  base = P_WR2; }
    else if (idx < P_ATT2) { p = a.src[9];  base = P_BR2; }
    else if (idx < P_BIAS2){ p = a.src[10]; base = P_ATT2; }
    else                   { p = a.src[11]; base = P_BIAS2; }
    int li = idx - base;
    par[idx] = flag ? ((const float*)p)[li] : (float)((const bf16*)p)[li];
    return;
  }
  b -= B_CVT;
  if (b < B_XP) {                        // ---- x -> xb (N x 64, zero-pad K) ----
    const int flag = detect_f32_wave(a.x);
    int i = b * 256 + tid;               // n*64 + k
    int n = i >> 6, k = i & 63;
    float v = 0.f;
    if (k < IN_F) {
      int idx = n * IN_F + k;
      v = flag ? ((const float*)a.x)[idx] : (float)((const bf16*)a.x)[idx];
    }
    xb[i] = (bf16)v;
    return;
  }
  b -= B_XP;
  if (b < B_W1) {                        // ---- Wt1[n][k] 512x64 ----
    const int flag = detect_f32_wave(a.x);
    int i = b * 256 + tid;
    int n = i >> 6, k = i & 63;
    float v = 0.f;
    if (k < IN_F) {
      const void* W = (n < F1) ? a.src[0] : a.src[2];
      int col = (n < F1) ? n : n - F1;
      int idx = k * F1 + col;
      v = flag ? ((const float*)W)[idx] : (float)((const bf16*)W)[idx];
    }
    wt1[i] = (bf16)v;
    return;
  }
  b -= B_W1;
  if (b < B_W2) {                        // ---- Wt2[n][k] 256x256 ----
    const int flag = detect_f32_wave(a.x);
    int i = b * 256 + tid;
    int n = i >> 8, k = i & 255;
    const void* W = (n < F2) ? a.src[6] : a.src[8];
    int col = (n < F2) ? n : n - F2;
    int idx = k * F2 + col;
    float v = flag ? ((const float*)W)[idx] : (float)((const bf16*)W)[idx];
    wt2[i] = (bf16)v;
    return;
  }
  b -= B_W2;
  if (b < B_BND) {                       // ---- graph bounds (batch sorted) ----
    int n = b * 256 + tid;
    if (n >= N_NODES) return;
    int bb = a.batch[n];
    if (n == 0) gs[bb] = 0;
    else {
      int bp = a.batch[n - 1];
      if (bp != bb) { gs[bb] = n; ge[bp] = n - 1; }
    }
    if (n == N_NODES - 1) ge[bb] = N_NODES - 1;
    return;
  }
  b -= B_BND;
  {                                      // ---- degree count ----
    int e = b * 256 + tid;
    if (e >= TOT_E) return;
    int dst = (e < N_EDGES) ? a.ei[N_EDGES + e] : (e - N_EDGES);
    atomicAdd(&cnt[dst], 1);
  }
}

// ---------------- fused: GEMM1 (MFMA) || scatter ----------------
// blocks [0,GBLK): xb(N,64) @ Wt1^T -> xl1|xr1. blocks [GBLK,GBLK+EBL): CSR scatter.
// Independent stages fused into one dispatch so scatter's atomic latency hides
// under gemm1's MFMA + store traffic (single-stream serialization -> max not sum).
__global__ __launch_bounds__(256) void gemm1_scatter_k(
    const bf16* __restrict__ xb, const bf16* __restrict__ wt1,
    const float* __restrict__ par,
    bf16* __restrict__ xl1, bf16* __restrict__ xr1,
    const int* __restrict__ ei, int* __restrict__ cursor,
    int* __restrict__ csr) {
  if (blockIdx.x >= GBLK) {              // ---- scatter path ----
    int e = (blockIdx.x - GBLK) * 256 + threadIdx.x;
    if (e >= TOT_E) return;
    int src, dst;
    if (e < N_EDGES) { src = ei[e]; dst = ei[N_EDGES + e]; }
    else             { src = dst = e - N_EDGES; }
    int pos = atomicAdd(&cursor[dst], 1);
    csr[pos] = src;
    return;
  }
  // ---- gemm1 path ----
  const int w = threadIdx.x >> 6, lane = threadIdx.x & 63;
  const int m0 = blockIdx.x * 32 + (w & 1) * 16;
  const int colbase = (w >> 1) * 256;
  const int lm = lane & 15, lk = lane >> 4;

  int arow = m0 + lm; if (arow >= N_NODES) arow = N_NODES - 1;
  const short8 a0 = *(const short8*)(xb + (size_t)arow * 64 + lk * 8);
  const short8 a1 = *(const short8*)(xb + (size_t)arow * 64 + 32 + lk * 8);

  f32x4 acc[16];
  const f32x4 z = {0.f, 0.f, 0.f, 0.f};
#pragma unroll
  for (int nt = 0; nt < 16; nt++) acc[nt] = z;

#pragma unroll
  for (int nt = 0; nt < 16; nt++) {
    int n = colbase + nt * 16 + lm;
    short8 b0 = *(const short8*)(wt1 + (size_t)n * 64 + lk * 8);
    short8 b1 = *(const short8*)(wt1 + (size_t)n * 64 + 32 + lk * 8);
    acc[nt] = __builtin_amdgcn_mfma_f32_16x16x32_bf16(a0, b0, acc[nt], 0, 0, 0);
    acc[nt] = __builtin_amdgcn_mfma_f32_16x16x32_bf16(a1, b1, acc[nt], 0, 0, 0);
  }

  const int r0 = m0 + (lane >> 4) * 4;
#pragma unroll
  for (int nt = 0; nt < 16; nt++) {
    int col = colbase + nt * 16 + lm;
    bf16* dst = (col < F1) ? xl1 : xr1;
    int c = (col < F1) ? col : col - F1;
    float bv = (col < F1) ? par[P_BL1 + c] : par[P_BR1 + c];
#pragma unroll
    for (int reg = 0; reg < 4; reg++) {
      int row = r0 + reg;
      if (row < N_NODES)
        dst[(size_t)row * F1 + c] = (bf16)(acc[nt][reg] + bv);
    }
  }
}

// ---------------- GEMM 2 (MFMA): h(N,256) @ Wt2^T -> xl2|xr2 (N,128 each) ----------------
__global__ __launch_bounds__(256) void gemm2_mfma_k(
    const bf16* __restrict__ h, const bf16* __restrict__ wt2,
    const float* __restrict__ par,
    bf16* __restrict__ xl2, bf16* __restrict__ xr2) {
  const int w = threadIdx.x >> 6, lane = threadIdx.x & 63;
  const int m0 = blockIdx.x * 32 + (w & 1) * 16;
  const int colbase = (w >> 1) * 128;
  const int lm = lane & 15, lk = lane >> 4;

  int arow = m0 + lm; if (arow >= N_NODES) arow = N_NODES - 1;
  const bf16* hrow = h + (size_t)arow * F1 + lk * 8;

  f32x4 acc[8];
  const f32x4 z = {0.f, 0.f, 0.f, 0.f};
#pragma unroll
  for (int nt = 0; nt < 8; nt++) acc[nt] = z;

#pragma unroll
  for (int kk = 0; kk < 256; kk += 32) {
    short8 a = *(const short8*)(hrow + kk);
#pragma unroll
    for (int nt = 0; nt < 8; nt++) {
      int n = colbase + nt * 16 + lm;
      short8 b = *(const short8*)(wt2 + (size_t)n * 256 + kk + lk * 8);
      acc[nt] = __builtin_amdgcn_mfma_f32_16x16x32_bf16(a, b, acc[nt], 0, 0, 0);
    }
  }

  const int r0 = m0 + (lane >> 4) * 4;
#pragma unroll
  for (int nt = 0; nt < 8; nt++) {
    int col = colbase + nt * 16 + lm;
    bf16* dst = (col < F2) ? xl2 : xr2;
    int c = (col < F2) ? col : col - F2;
    float bv = (col < F2) ? par[P_BL2 + c] : par[P_BR2 + c];
#pragma unroll
    for (int reg = 0; reg < 4; reg++) {
      int row = r0 + reg;
      if (row < N_NODES)
        dst[(size_t)row * F2 + c] = (bf16)(acc[nt][reg] + bv);
    }
  }
}

// ---------------- CSR scan (3-phase, multi-block) ----------------
__global__ __launch_bounds__(1024) void scan_a(const int* __restrict__ cnt,
                                               int* __restrict__ offs,
                                               int* __restrict__ bsum) {
  __shared__ int wsum[16];
  const int t = threadIdx.x;
  const int lane = t & 63, w = t >> 6;
  int idx = blockIdx.x * 1024 + t;
  int v = (idx < N_NODES) ? cnt[idx] : 0;
  int s = v;
#pragma unroll
  for (int off = 1; off < 64; off <<= 1) {
    int u = __shfl_up(s, off, 64);
    if (lane >= off) s += u;
  }
  if (lane == 63) wsum[w] = s;
  __syncthreads();
  int prefix = 0;
  for (int i = 0; i < w; i++) prefix += wsum[i];
  if (idx < N_NODES) offs[idx] = prefix + s - v;   // exclusive within block
  if (t == 1023) bsum[blockIdx.x] = prefix + s;    // block total
}

__global__ void scan_b(const int* __restrict__ bsum, int* __restrict__ boff,
                       int* __restrict__ offs) {
  const int lane = threadIdx.x;   // 64 threads, SCAN_BLKS<=64 values
  int v = (lane < SCAN_BLKS) ? bsum[lane] : 0;
  int s = v;
#pragma unroll
  for (int off = 1; off < 64; off <<= 1) {
    int u = __shfl_up(s, off, 64);
    if (lane >= off) s += u;
  }
  if (lane < SCAN_BLKS) boff[lane] = s - v;
  if (lane == SCAN_BLKS - 1) offs[N_NODES] = s;   // grand total
}

__global__ void scan_c(const int* __restrict__ boff, int* __restrict__ offs,
                       int* __restrict__ cursor) {
  int idx = blockIdx.x * 256 + threadIdx.x;
  if (idx >= N_NODES) return;
  int o = offs[idx] + boff[idx >> 10];
  offs[idx] = o;
  cursor[idx] = o;
}

// ---------------- layer-1 aggregation: one wave per dst, 2 groups x 32 lanes,
// register double-buffer prefetch of the next edge's row ----------------
__global__ __launch_bounds__(256, 4) void agg1_k(
    const bf16* __restrict__ xl1, const bf16* __restrict__ xr1,
    const float* __restrict__ par,
    const int* __restrict__ offs, const int* __restrict__ csr,
    bf16* __restrict__ hout) {
  const int dst = blockIdx.x * 4 + (threadIdx.x >> 6);
  if (dst >= N_NODES) return;
  const int lane = threadIdx.x & 63;
  const int g = lane >> 5;        // 2 edge groups
  const int sl = lane & 31;
  const int chb = sl * 8;

  f2 r2[4], a2[4];
  load8bf2(xr1 + (size_t)dst * F1 + chb, r2);
  {
    float4 aa = *(const float4*)(par + P_ATT1 + chb);
    float4 ab = *(const float4*)(par + P_ATT1 + chb + 4);
    a2[0].x = aa.x; a2[0].y = aa.y; a2[1].x = aa.z; a2[1].y = aa.w;
    a2[2].x = ab.x; a2[2].y = ab.y; a2[3].x = ab.z; a2[3].y = ab.w;
  }

  const int e0 = offs[dst], e1 = offs[dst + 1];
  const f2 zf2 = {0.f, 0.f};
  f2 acc2[4];
#pragma unroll
  for (int j = 0; j < 4; j++) acc2[j] = zf2;
  float denom = 0.f;

  // prime the pipeline: edge e0+g
  int e = e0 + g;
  const uint4 zq = {0, 0, 0, 0};
  bool valid = e < e1;
  uint4 q = valid ? *(const uint4*)(xl1 + (size_t)csr[e] * F1 + chb) : zq;

  for (int base = e0; base < e1; base += 2) {
    const uint4 qc = q;
    const bool vc = valid;
    // prefetch next edge's row before touching qc
    e += 2;
    valid = e < e1;
    q = valid ? *(const uint4*)(xl1 + (size_t)csr[e] * F1 + chb) : zq;

    f2 v2[4];
    unpack8bf2(qc, v2);     // invalid -> zeros
    f2 lt2 = zf2;
#pragma unroll
    for (int j = 0; j < 4; j++)
      lt2 = lrelu2(v2[j] + r2[j]) * a2[j] + lt2;
    float lt = vc ? (lt2.x + lt2.y) : -1e30f;
    // per-head reduce over this lane's 8-lane head subgroup
    lt += __shfl_xor(lt, 1, 64);
    lt += __shfl_xor(lt, 2, 64);
    lt += __shfl_xor(lt, 4, 64);
    float p = __expf(fminf(lt, 60.f));   // logits O(1); invalid group -> 0
    denom += p;
    f2 pv; pv.x = p; pv.y = p;
#pragma unroll
    for (int j = 0; j < 4; j++) acc2[j] = pv * v2[j] + acc2[j];
  }

  // combine the 2 edge groups (lane ^ 32 has same channels & head)
  denom += __shfl_xor(denom, 32, 64);
#pragma unroll
  for (int j = 0; j < 4; j++) {
    acc2[j].x += __shfl_xor(acc2[j].x, 32, 64);
    acc2[j].y += __shfl_xor(acc2[j].y, 32, 64);
  }

  if (g == 0) {
    float inv = 1.f / (denom + EPS_A);
    __align__(16) bf16 ob[8];
#pragma unroll
    for (int j = 0; j < 4; j++) {
      float o0 = fmaxf(acc2[j].x * inv + par[P_BIAS1 + chb + 2*j],     0.f);
      float o1 = fmaxf(acc2[j].y * inv + par[P_BIAS1 + chb + 2*j + 1], 0.f);
      ob[2*j] = (bf16)o0; ob[2*j+1] = (bf16)o1;
    }
    *(uint4*)(hout + (size_t)dst * F1 + chb) = *(uint4*)ob;
  }
}

// ---------------- layer-2 aggregation: one wave per dst, 4 groups x 16 lanes,
// 8 ch/lane (single 16B load) + register prefetch — mirrors agg1's win ----------------
__global__ __launch_bounds__(256, 4) void agg2_k(
    const bf16* __restrict__ xl2, const bf16* __restrict__ xr2,
    const float* __restrict__ par,
    const int* __restrict__ offs, const int* __restrict__ csr,
    bf16* __restrict__ h2) {
  const int dst = blockIdx.x * 4 + (threadIdx.x >> 6);
  if (dst >= N_NODES) return;
  const int lane = threadIdx.x & 63;
  const int g = lane >> 4;        // 4 edge groups
  const int sl = lane & 15;
  const int chb = sl * 8;

  f2 r2[4], a2[4];
  load8bf2(xr2 + (size_t)dst * F2 + chb, r2);
  {
    float4 aa = *(const float4*)(par + P_ATT2 + chb);
    float4 ab = *(const float4*)(par + P_ATT2 + chb + 4);
    a2[0].x = aa.x; a2[0].y = aa.y; a2[1].x = aa.z; a2[1].y = aa.w;
    a2[2].x = ab.x; a2[2].y = ab.y; a2[3].x = ab.z; a2[3].y = ab.w;
  }

  const int e0 = offs[dst], e1 = offs[dst + 1];
  const f2 zf2 = {0.f, 0.f};
  f2 acc2[4];
#pragma unroll
  for (int j = 0; j < 4; j++) acc2[j] = zf2;
  float denom = 0.f;

  const uint4 zq = {0, 0, 0, 0};
  int e = e0 + g;
  bool valid = e < e1;
  uint4 q = valid ? *(const uint4*)(xl2 + (size_t)csr[e] * F2 + chb) : zq;

  for (int base = e0; base < e1; base += 4) {
    const uint4 qc = q;
    const bool vc = valid;
    e += 4;
    valid = e < e1;
    q = valid ? *(const uint4*)(xl2 + (size_t)csr[e] * F2 + chb) : zq;

    f2 v2[4];
    unpack8bf2(qc, v2);
    f2 lt2 = zf2;
#pragma unroll
    for (int j = 0; j < 4; j++)
      lt2 = lrelu2(v2[j] + r2[j]) * a2[j] + lt2;
    float lt = vc ? (lt2.x + lt2.y) : -1e30f;
    // reduce over the 16-lane group
    lt += __shfl_xor(lt, 1, 64);
    lt += __shfl_xor(lt, 2, 64);
    lt += __shfl_xor(lt, 4, 64);
    lt += __shfl_xor(lt, 8, 64);
    float p = __expf(fminf(lt, 60.f));
    denom += p;
    f2 pv; pv.x = p; pv.y = p;
#pragma unroll
    for (int j = 0; j < 4; j++) acc2[j] = pv * v2[j] + acc2[j];
  }

  // combine the 4 edge groups (lanes ^16 / ^32 share channels)
#pragma unroll
  for (int m = 16; m <= 32; m <<= 1) {
    denom += __shfl_xor(denom, m, 64);
#pragma unroll
    for (int j = 0; j < 4; j++) {
      acc2[j].x += __shfl_xor(acc2[j].x, m, 64);
      acc2[j].y += __shfl_xor(acc2[j].y, m, 64);
    }
  }

  if (g == 0) {
    float inv = 1.f / (denom + EPS_A);
    __align__(16) bf16 ob[8];
#pragma unroll
    for (int j = 0; j < 4; j++) {
      float o0 = fmaxf(acc2[j].x * inv + par[P_BIAS2 + chb + 2*j],     0.f);
      float o1 = fmaxf(acc2[j].y * inv + par[P_BIAS2 + chb + 2*j + 1], 0.f);
      ob[2*j] = (bf16)o0; ob[2*j+1] = (bf16)o1;
    }
    *(uint4*)(h2 + (size_t)dst * F2 + chb) = *(uint4*)ob;
  }
}

// ---------------- pooling ----------------
__global__ __launch_bounds__(256) void pool_k(
    const bf16* __restrict__ h2, const int* __restrict__ gs,
    const int* __restrict__ ge, const void* __restrict__ x,
    void* __restrict__ out) {
  const int flag = detect_f32_wave(x);
  const int g = blockIdx.x;
  const int t = threadIdx.x;
  const int c = t & 127, half = t >> 7;
  int s = gs[g], e = ge[g];
  if (s < 0 || e < s) { s = 0; e = -1; }   // empty graph (memset-init) -> 0
  float sum = 0.f;
  for (int n = s + half; n <= e; n += 2)
    sum += (float)h2[(size_t)n * F2 + c];
  __shared__ float red[128];
  if (half == 1) red[c] = sum;
  __syncthreads();
  if (half == 0) {
    float tot = sum + red[c];
    float cnt = (e >= s) ? (float)(e - s + 1) : 1.f;
    float v = tot / cnt;
    if (flag) ((float*)out)[g * F2 + c] = v;
    else      ((bf16*)out)[g * F2 + c] = (bf16)v;
  }
}

// ---------------- launch ----------------
extern "C" void kernel_launch(void* const* d_in, const int* in_sizes, int n_in,
                              void* d_out, int out_size, void* d_ws, size_t ws_size,
                              hipStream_t stream) {
  (void)in_sizes; (void)n_in; (void)out_size; (void)ws_size;
  const void* x     = d_in[0];
  const int*  ei    = (const int*)d_in[1];
  const int*  batch = (const int*)d_in[2];

  char* ws = (char*)d_ws;
  float* par  = (float*)(ws + OFF_PAR);
  bf16* xl1 = (bf16*)(ws + OFF_XL1);
  bf16* xr1 = (bf16*)(ws + OFF_XR1);
  bf16* h   = (bf16*)(ws + OFF_H);
  bf16* xl2 = (bf16*)(ws + OFF_XL2);
  bf16* xr2 = (bf16*)(ws + OFF_XR2);
  bf16* h2  = (bf16*)(ws + OFF_H2);
  bf16* xb  = (bf16*)(ws + OFF_XB);
  bf16* wt1 = (bf16*)(ws + OFF_WT1);
  bf16* wt2 = (bf16*)(ws + OFF_WT2);
  int* cnt    = (int*)(ws + OFF_CNT);
  int* offs   = (int*)(ws + OFF_OFFS);
  int* cursor = (int*)(ws + OFF_CUR);
  int* csr    = (int*)(ws + OFF_CSR);
  int* gs     = (int*)(ws + OFF_GS);
  int* ge     = (int*)(ws + OFF_GE);
  int* bsum   = (int*)(ws + OFF_BS);
  int* boff   = (int*)(ws + OFF_BO);

  hipMemsetAsync(cnt, 0, (size_t)N_NODES * 4, stream);
  hipMemsetAsync(gs, 0xFF, (size_t)(OFF_WT1 - OFF_GS), stream);  // gs/ge = -1

  PrepArgs pa;
  pa.x = x; pa.ei = ei; pa.batch = batch;
  for (int i = 0; i < 12; i++) pa.src[i] = d_in[3 + i];
  const int prep_blocks = B_CVT + B_XP + B_W1 + B_W2 + B_BND + B_CNT;
  prep_k<<<prep_blocks, 256, 0, stream>>>(pa, par, xb, wt1, wt2, gs, ge, cnt);

  scan_a<<<SCAN_BLKS, 1024, 0, stream>>>(cnt, offs, bsum);
  scan_b<<<1, 64, 0, stream>>>(bsum, boff, offs);
  scan_c<<<(N_NODES + 255) / 256, 256, 0, stream>>>(boff, offs, cursor);

  gemm1_scatter_k<<<GBLK + EBL, 256, 0, stream>>>(xb, wt1, par, xl1, xr1,
                                                  ei, cursor, csr);
  agg1_k<<<(N_NODES + 3) / 4, 256, 0, stream>>>(xl1, xr1, par, offs, csr, h);
  gemm2_mfma_k<<<GBLK, 256, 0, stream>>>(h, wt2, par, xl2, xr2);
  agg2_k<<<(N_NODES + 3) / 4, 256, 0, stream>>>(xl2, xr2, par, offs, csr, h2);
  pool_k<<<NGRAPH, 256, 0, stream>>>(h2, gs, ge, x, d_out);
}

// Round 11
// 442.401 us; speedup vs baseline: 1.3423x; 1.0497x over previous
//
#include <hip/hip_runtime.h>
#include <hip/hip_bf16.h>
#include <limits.h>

// ---------------- problem constants ----------------
#define N_NODES 50000
#define N_EDGES 800000
#define TOT_E   (N_EDGES + N_NODES)   // with self loops
#define IN_F    38
#define HIDC    64
#define NH      4
#define F1      256                    // NH*HIDC
#define F2      128                    // OUT
#define NGRAPH  128
#define NEG_SLOPE 0.2f
#define EPS_A   1e-16f

typedef __hip_bfloat16 bf16;
typedef __attribute__((ext_vector_type(8))) short short8;
typedef __attribute__((ext_vector_type(16))) float f32x16;
typedef __attribute__((ext_vector_type(2))) float f2;   // lowers to VOP3P v_pk_*_f32

// ---------------- ws layout ----------------
constexpr size_t al256(size_t x) { return (x + 255) & ~(size_t)255; }

// converted-params element offsets (f32 elements) — contiguous in this order
#define P_WL1   0
#define P_BL1   (P_WL1 + IN_F * F1)        // 9728
#define P_WR1   (P_BL1 + F1)               // 9984
#define P_BR1   (P_WR1 + IN_F * F1)        // 19712
#define P_ATT1  (P_BR1 + F1)               // 19968
#define P_BIAS1 (P_ATT1 + F1)              // 20224
#define P_WL2   (P_BIAS1 + F1)             // 20480
#define P_BL2   (P_WL2 + F1 * F2)          // 53248
#define P_WR2   (P_BL2 + F2)               // 53376
#define P_BR2   (P_WR2 + F1 * F2)          // 86144
#define P_ATT2  (P_BR2 + F2)               // 86272
#define P_BIAS2 (P_ATT2 + F2)              // 86400
#define P_TOTAL (P_BIAS2 + F2)             // 86528 = 338*256 exactly

constexpr size_t OFF_PAR  = 256;
constexpr size_t OFF_XL1  = OFF_PAR + al256((size_t)P_TOTAL * 4);   // reused as h2 later
constexpr size_t OFF_XR1  = OFF_XL1 + al256((size_t)N_NODES * F1 * 2);
constexpr size_t OFF_H    = OFF_XR1 + al256((size_t)N_NODES * F1 * 2);
constexpr size_t OFF_XL2  = OFF_H   + al256((size_t)N_NODES * F1 * 2);
constexpr size_t OFF_XR2  = OFF_XL2 + al256((size_t)N_NODES * F2 * 2);
constexpr size_t OFF_CNT  = OFF_XR2 + al256((size_t)N_NODES * F2 * 2);
constexpr size_t OFF_OFFS = OFF_CNT + al256((size_t)N_NODES * 4);
constexpr size_t OFF_CUR  = OFF_OFFS+ al256((size_t)(N_NODES + 1) * 4);
constexpr size_t OFF_CSR  = OFF_CUR + al256((size_t)(N_NODES + 1) * 4);
constexpr size_t OFF_GS   = OFF_CSR + al256((size_t)TOT_E * 4);
constexpr size_t OFF_GE   = OFF_GS  + al256((size_t)NGRAPH * 4);    // adjacent to GS
constexpr size_t OFF_WT1  = OFF_GE  + al256((size_t)NGRAPH * 4);    // 512x64 bf16
constexpr size_t OFF_WT2  = OFF_WT1 + al256((size_t)512 * 64 * 2);  // 256x256 bf16
constexpr size_t OFF_BS   = OFF_WT2 + al256((size_t)256 * 256 * 2); // 49 block sums
constexpr size_t OFF_BO   = OFF_BS  + al256(64 * 4);                // 49 block offsets
constexpr size_t OFF_H2   = OFF_XL1;  // xl1 dead after agg1
constexpr size_t OFF_XB   = OFF_H;    // xb (N x 64 bf16) dead before agg1 writes h

#define SCAN_BLKS 49   // ceil(50000/1024)
#define GBLK 1563      // ceil(50000/32)  gemm row-blocks
#define SBL  831       // ceil(TOT_E/1024) scatter blocks (4 edges/thread)

// ---------------- helpers ----------------
// uint4 (8 bf16) -> 4 x f2; pairs are (ch 2i, ch 2i+1)
__device__ __forceinline__ void unpack8bf2(uint4 q, f2* f) {
  unsigned v[4] = {q.x, q.y, q.z, q.w};
#pragma unroll
  for (int i = 0; i < 4; i++) {
    f2 t;
    t.x = __uint_as_float(v[i] << 16);
    t.y = __uint_as_float(v[i] & 0xffff0000u);
    f[i] = t;
  }
}

__device__ __forceinline__ void load8bf2(const bf16* __restrict__ p, f2* f) {
  unpack8bf2(*(const uint4*)p, f);
}

// leaky_relu(s) = 0.6*s + 0.4*|s|
__device__ __forceinline__ f2 lrelu2(f2 s) {
  f2 as;
  as.x = __uint_as_float(__float_as_uint(s.x) & 0x7fffffffu);
  as.y = __uint_as_float(__float_as_uint(s.y) & 0x7fffffffu);
  return 0.6f * s + 0.4f * as;
}

// wave-cooperative dtype sniff: 1 = inputs are f32, 0 = bf16.
__device__ __forceinline__ int detect_f32_wave(const void* __restrict__ x) {
  const unsigned short* u = (const unsigned short*)x;
  unsigned short b = u[threadIdx.x & 63];
  int e = (b >> 7) & 0xFF;
  unsigned long long m = __ballot(!((e == 0) || (e >= 96 && e <= 158)));
  return __popcll(m) > 8;
}

// ---------------- fused prep kernel ----------------
#define B_CVT  338
#define B_XP   12500
#define B_W1   128
#define B_W2   256
#define B_BND  196
#define B_CNT  3321

struct PrepArgs {
  const void* x;
  const void* src[12];     // Wl1,bl1,Wr1,br1,att1,bias1,Wl2,bl2,Wr2,br2,att2,bias2
  const int* ei;
  const int* batch;
};

__global__ __launch_bounds__(256) void prep_k(
    PrepArgs a, float* __restrict__ par, bf16* __restrict__ xb,
    bf16* __restrict__ wt1, bf16* __restrict__ wt2,
    int* __restrict__ gs, int* __restrict__ ge, int* __restrict__ cnt) {
  int b = blockIdx.x;
  const int tid = threadIdx.x;

  if (b < B_CVT) {                       // ---- param convert -> f32 ----
    const int flag = detect_f32_wave(a.x);
    int idx = b * 256 + tid;             // [0, P_TOTAL)
    const void* p; int base;
    if      (idx < P_BL1)  { p = a.src[0];  base = P_WL1; }
    else if (idx < P_WR1)  { p = a.src[1];  base = P_BL1; }
    else if (idx < P_BR1)  { p = a.src[2];  base = P_WR1; }
    else if (idx < P_ATT1) { p = a.src[3];  base = P_BR1; }
    else if (idx < P_BIAS1){ p = a.src[4];  base = P_ATT1; }
    else if (idx < P_WL2)  { p = a.src[5];  base = P_BIAS1; }
    else if (idx < P_BL2)  { p = a.src[6];  base = P_WL2; }
    else if (idx < P_WR2)  { p = a.src[7];  base = P_BL2; }
    else if (idx < P_BR2)  { p = a.src[8];  base = P_WR2; }
    else if (idx < P_ATT2) { p = a.src[9];  base = P_BR2; }
    else if (idx < P_BIAS2){ p = a.src[10]; base = P_ATT2; }
    else                   { p = a.src[11]; base = P_BIAS2; }
    int li = idx - base;
    par[idx] = flag ? ((const float*)p)[li] : (float)((const bf16*)p)[li];
    return;
  }
  b -= B_CVT;
  if (b < B_XP) {                        // ---- x -> xb (N x 64, zero-pad K) ----
    const int flag = detect_f32_wave(a.x);
    int i = b * 256 + tid;               // n*64 + k
    int n = i >> 6, k = i & 63;
    float v = 0.f;
    if (k < IN_F) {
      int idx = n * IN_F + k;
      v = flag ? ((const float*)a.x)[idx] : (float)((const bf16*)a.x)[idx];
    }
    xb[i] = (bf16)v;
    return;
  }
  b -= B_XP;
  if (b < B_W1) {                        // ---- Wt1[n][k] 512x64 ----
    const int flag = detect_f32_wave(a.x);
    int i = b * 256 + tid;
    int n = i >> 6, k = i & 63;
    float v = 0.f;
    if (k < IN_F) {
      const void* W = (n < F1) ? a.src[0] : a.src[2];
      int col = (n < F1) ? n : n - F1;
      int idx = k * F1 + col;
      v = flag ? ((const float*)W)[idx] : (float)((const bf16*)W)[idx];
    }
    wt1[i] = (bf16)v;
    return;
  }
  b -= B_W1;
  if (b < B_W2) {                        // ---- Wt2[n][k] 256x256 ----
    const int flag = detect_f32_wave(a.x);
    int i = b * 256 + tid;
    int n = i >> 8, k = i & 255;
    const void* W = (n < F2) ? a.src[6] : a.src[8];
    int col = (n < F2) ? n : n - F2;
    int idx = k * F2 + col;
    float v = flag ? ((const float*)W)[idx] : (float)((const bf16*)W)[idx];
    wt2[i] = (bf16)v;
    return;
  }
  b -= B_W2;
  if (b < B_BND) {                       // ---- graph bounds (batch sorted) ----
    int n = b * 256 + tid;
    if (n >= N_NODES) return;
    int bb = a.batch[n];
    if (n == 0) gs[bb] = 0;
    else {
      int bp = a.batch[n - 1];
      if (bp != bb) { gs[bb] = n; ge[bp] = n - 1; }
    }
    if (n == N_NODES - 1) ge[bb] = N_NODES - 1;
    return;
  }
  b -= B_BND;
  {                                      // ---- degree count ----
    int e = b * 256 + tid;
    if (e >= TOT_E) return;
    int dst = (e < N_EDGES) ? a.ei[N_EDGES + e] : (e - N_EDGES);
    atomicAdd(&cnt[dst], 1);
  }
}

// ---------------- fused: GEMM1 (MFMA 32x32x16, full-line stores) || scatter ----------------
// blocks [0,GBLK): xb(N,64) @ Wt1^T -> xl1|xr1. blocks [GBLK,GBLK+SBL): CSR scatter
// at 4 edges/thread for atomic-latency overlap.
__global__ __launch_bounds__(256) void gemm1_scatter_k(
    const bf16* __restrict__ xb, const bf16* __restrict__ wt1,
    const float* __restrict__ par,
    bf16* __restrict__ xl1, bf16* __restrict__ xr1,
    const int* __restrict__ ei, int* __restrict__ cursor,
    int* __restrict__ csr) {
  if (blockIdx.x >= GBLK) {              // ---- scatter path ----
    int base = (blockIdx.x - GBLK) * 1024 + threadIdx.x;
    int srcv[4], dstv[4];
    bool val[4];
#pragma unroll
    for (int i = 0; i < 4; i++) {
      int e = base + i * 256;
      val[i] = e < TOT_E;
      if (val[i]) {
        if (e < N_EDGES) { srcv[i] = ei[e]; dstv[i] = ei[N_EDGES + e]; }
        else             { srcv[i] = dstv[i] = e - N_EDGES; }
      }
    }
    int pos[4];
#pragma unroll
    for (int i = 0; i < 4; i++)
      if (val[i]) pos[i] = atomicAdd(&cursor[dstv[i]], 1);
#pragma unroll
    for (int i = 0; i < 4; i++)
      if (val[i]) __builtin_nontemporal_store(srcv[i], &csr[pos[i]]);
    return;
  }
  // ---- gemm1 path: 32x32x16 MFMA. Wave w: rows blk*32..+31, cols w*128..+127 ----
  const int w = threadIdx.x >> 6, lane = threadIdx.x & 63;
  const int m0 = blockIdx.x * 32;
  const int colbase = w * 128;
  const int lm = lane & 31;       // m / n index
  const int kh = lane >> 5;       // k-half (8 of 16)

  int arow = m0 + lm; if (arow >= N_NODES) arow = N_NODES - 1;
  short8 afr[4];
#pragma unroll
  for (int kk = 0; kk < 4; kk++)
    afr[kk] = *(const short8*)(xb + (size_t)arow * 64 + kk * 16 + kh * 8);

  f32x16 acc[4] = {};
#pragma unroll
  for (int t = 0; t < 4; t++) {
    int n = colbase + t * 32 + lm;
#pragma unroll
    for (int kk = 0; kk < 4; kk++) {
      short8 b = *(const short8*)(wt1 + (size_t)n * 64 + kk * 16 + kh * 8);
      acc[t] = __builtin_amdgcn_mfma_f32_32x32x16_bf16(afr[kk], b, acc[t], 0, 0, 0);
    }
  }

  // C/D: col = lane&31 (+tile), row = (reg&3) + 8*(reg>>2) + 4*kh  [m74/m101]
#pragma unroll
  for (int t = 0; t < 4; t++) {
    int col = colbase + t * 32 + lm;
    bf16* dst = (col < F1) ? xl1 : xr1;
    int c = (col < F1) ? col : col - F1;
    float bv = (col < F1) ? par[P_BL1 + c] : par[P_BR1 + c];
#pragma unroll
    for (int reg = 0; reg < 16; reg++) {
      int row = m0 + (reg & 3) + 8 * (reg >> 2) + 4 * kh;
      if (row < N_NODES)
        dst[(size_t)row * F1 + c] = (bf16)(acc[t][reg] + bv);
    }
  }
}

// ---------------- GEMM 2 (MFMA 32x32x16): h(N,256) @ Wt2^T -> xl2|xr2 ----------------
// Wave w: rows blk*32..+31, cols w*64..+63 (2 tiles).
__global__ __launch_bounds__(256) void gemm2_mfma_k(
    const bf16* __restrict__ h, const bf16* __restrict__ wt2,
    const float* __restrict__ par,
    bf16* __restrict__ xl2, bf16* __restrict__ xr2) {
  const int w = threadIdx.x >> 6, lane = threadIdx.x & 63;
  const int m0 = blockIdx.x * 32;
  const int colbase = w * 64;
  const int lm = lane & 31;
  const int kh = lane >> 5;

  int arow = m0 + lm; if (arow >= N_NODES) arow = N_NODES - 1;
  const bf16* hrow = h + (size_t)arow * F1 + kh * 8;

  f32x16 acc[2] = {};
#pragma unroll
  for (int kk = 0; kk < 16; kk++) {
    short8 a = *(const short8*)(hrow + kk * 16);
#pragma unroll
    for (int t = 0; t < 2; t++) {
      int n = colbase + t * 32 + lm;
      short8 b = *(const short8*)(wt2 + (size_t)n * 256 + kk * 16 + kh * 8);
      acc[t] = __builtin_amdgcn_mfma_f32_32x32x16_bf16(a, b, acc[t], 0, 0, 0);
    }
  }

#pragma unroll
  for (int t = 0; t < 2; t++) {
    int col = colbase + t * 32 + lm;
    bf16* dst = (col < F2) ? xl2 : xr2;
    int c = (col < F2) ? col : col - F2;
    float bv = (col < F2) ? par[P_BL2 + c] : par[P_BR2 + c];
#pragma unroll
    for (int reg = 0; reg < 16; reg++) {
      int row = m0 + (reg & 3) + 8 * (reg >> 2) + 4 * kh;
      if (row < N_NODES)
        dst[(size_t)row * F2 + c] = (bf16)(acc[t][reg] + bv);
    }
  }
}

// ---------------- CSR scan (3-phase, multi-block) ----------------
__global__ __launch_bounds__(1024) void scan_a(const int* __restrict__ cnt,
                                               int* __restrict__ offs,
                                               int* __restrict__ bsum) {
  __shared__ int wsum[16];
  const int t = threadIdx.x;
  const int lane = t & 63, w = t >> 6;
  int idx = blockIdx.x * 1024 + t;
  int v = (idx < N_NODES) ? cnt[idx] : 0;
  int s = v;
#pragma unroll
  for (int off = 1; off < 64; off <<= 1) {
    int u = __shfl_up(s, off, 64);
    if (lane >= off) s += u;
  }
  if (lane == 63) wsum[w] = s;
  __syncthreads();
  int prefix = 0;
  for (int i = 0; i < w; i++) prefix += wsum[i];
  if (idx < N_NODES) offs[idx] = prefix + s - v;   // exclusive within block
  if (t == 1023) bsum[blockIdx.x] = prefix + s;    // block total
}

__global__ void scan_b(const int* __restrict__ bsum, int* __restrict__ boff,
                       int* __restrict__ offs) {
  const int lane = threadIdx.x;   // 64 threads, SCAN_BLKS<=64 values
  int v = (lane < SCAN_BLKS) ? bsum[lane] : 0;
  int s = v;
#pragma unroll
  for (int off = 1; off < 64; off <<= 1) {
    int u = __shfl_up(s, off, 64);
    if (lane >= off) s += u;
  }
  if (lane < SCAN_BLKS) boff[lane] = s - v;
  if (lane == SCAN_BLKS - 1) offs[N_NODES] = s;   // grand total
}

__global__ void scan_c(const int* __restrict__ boff, int* __restrict__ offs,
                       int* __restrict__ cursor) {
  int idx = blockIdx.x * 256 + threadIdx.x;
  if (idx >= N_NODES) return;
  int o = offs[idx] + boff[idx >> 10];
  offs[idx] = o;
  cursor[idx] = o;
}

// ---------------- layer-1 aggregation: one wave per dst, 2 groups x 32 lanes,
// register double-buffer prefetch of the next edge's row ----------------
__global__ __launch_bounds__(256, 4) void agg1_k(
    const bf16* __restrict__ xl1, const bf16* __restrict__ xr1,
    const float* __restrict__ par,
    const int* __restrict__ offs, const int* __restrict__ csr,
    bf16* __restrict__ hout) {
  const int dst = blockIdx.x * 4 + (threadIdx.x >> 6);
  if (dst >= N_NODES) return;
  const int lane = threadIdx.x & 63;
  const int g = lane >> 5;        // 2 edge groups
  const int sl = lane & 31;
  const int chb = sl * 8;

  f2 r2[4], a2[4];
  load8bf2(xr1 + (size_t)dst * F1 + chb, r2);
  {
    float4 aa = *(const float4*)(par + P_ATT1 + chb);
    float4 ab = *(const float4*)(par + P_ATT1 + chb + 4);
    a2[0].x = aa.x; a2[0].y = aa.y; a2[1].x = aa.z; a2[1].y = aa.w;
    a2[2].x = ab.x; a2[2].y = ab.y; a2[3].x = ab.z; a2[3].y = ab.w;
  }

  const int e0 = offs[dst], e1 = offs[dst + 1];
  const f2 zf2 = {0.f, 0.f};
  f2 acc2[4];
#pragma unroll
  for (int j = 0; j < 4; j++) acc2[j] = zf2;
  float denom = 0.f;

  // prime the pipeline: edge e0+g
  int e = e0 + g;
  const uint4 zq = {0, 0, 0, 0};
  bool valid = e < e1;
  uint4 q = valid ? *(const uint4*)(xl1 + (size_t)csr[e] * F1 + chb) : zq;

  for (int base = e0; base < e1; base += 2) {
    const uint4 qc = q;
    const bool vc = valid;
    // prefetch next edge's row before touching qc
    e += 2;
    valid = e < e1;
    q = valid ? *(const uint4*)(xl1 + (size_t)csr[e] * F1 + chb) : zq;

    f2 v2[4];
    unpack8bf2(qc, v2);     // invalid -> zeros
    f2 lt2 = zf2;
#pragma unroll
    for (int j = 0; j < 4; j++)
      lt2 = lrelu2(v2[j] + r2[j]) * a2[j] + lt2;
    float lt = vc ? (lt2.x + lt2.y) : -1e30f;
    // per-head reduce over this lane's 8-lane head subgroup
    lt += __shfl_xor(lt, 1, 64);
    lt += __shfl_xor(lt, 2, 64);
    lt += __shfl_xor(lt, 4, 64);
    float p = __expf(fminf(lt, 60.f));   // logits O(1); invalid group -> 0
    denom += p;
    f2 pv; pv.x = p; pv.y = p;
#pragma unroll
    for (int j = 0; j < 4; j++) acc2[j] = pv * v2[j] + acc2[j];
  }

  // combine the 2 edge groups (lane ^ 32 has same channels & head)
  denom += __shfl_xor(denom, 32, 64);
#pragma unroll
  for (int j = 0; j < 4; j++) {
    acc2[j].x += __shfl_xor(acc2[j].x, 32, 64);
    acc2[j].y += __shfl_xor(acc2[j].y, 32, 64);
  }

  if (g == 0) {
    float inv = 1.f / (denom + EPS_A);
    __align__(16) bf16 ob[8];
#pragma unroll
    for (int j = 0; j < 4; j++) {
      float o0 = fmaxf(acc2[j].x * inv + par[P_BIAS1 + chb + 2*j],     0.f);
      float o1 = fmaxf(acc2[j].y * inv + par[P_BIAS1 + chb + 2*j + 1], 0.f);
      ob[2*j] = (bf16)o0; ob[2*j+1] = (bf16)o1;
    }
    *(uint4*)(hout + (size_t)dst * F1 + chb) = *(uint4*)ob;
  }
}

// ---------------- layer-2 aggregation: one wave per dst, 4 groups x 16 lanes,
// 8 ch/lane (single 16B load) + register prefetch ----------------
__global__ __launch_bounds__(256, 4) void agg2_k(
    const bf16* __restrict__ xl2, const bf16* __restrict__ xr2,
    const float* __restrict__ par,
    const int* __restrict__ offs, const int* __restrict__ csr,
    bf16* __restrict__ h2) {
  const int dst = blockIdx.x * 4 + (threadIdx.x >> 6);
  if (dst >= N_NODES) return;
  const int lane = threadIdx.x & 63;
  const int g = lane >> 4;        // 4 edge groups
  const int sl = lane & 15;
  const int chb = sl * 8;

  f2 r2[4], a2[4];
  load8bf2(xr2 + (size_t)dst * F2 + chb, r2);
  {
    float4 aa = *(const float4*)(par + P_ATT2 + chb);
    float4 ab = *(const float4*)(par + P_ATT2 + chb + 4);
    a2[0].x = aa.x; a2[0].y = aa.y; a2[1].x = aa.z; a2[1].y = aa.w;
    a2[2].x = ab.x; a2[2].y = ab.y; a2[3].x = ab.z; a2[3].y = ab.w;
  }

  const int e0 = offs[dst], e1 = offs[dst + 1];
  const f2 zf2 = {0.f, 0.f};
  f2 acc2[4];
#pragma unroll
  for (int j = 0; j < 4; j++) acc2[j] = zf2;
  float denom = 0.f;

  const uint4 zq = {0, 0, 0, 0};
  int e = e0 + g;
  bool valid = e < e1;
  uint4 q = valid ? *(const uint4*)(xl2 + (size_t)csr[e] * F2 + chb) : zq;

  for (int base = e0; base < e1; base += 4) {
    const uint4 qc = q;
    const bool vc = valid;
    e += 4;
    valid = e < e1;
    q = valid ? *(const uint4*)(xl2 + (size_t)csr[e] * F2 + chb) : zq;

    f2 v2[4];
    unpack8bf2(qc, v2);
    f2 lt2 = zf2;
#pragma unroll
    for (int j = 0; j < 4; j++)
      lt2 = lrelu2(v2[j] + r2[j]) * a2[j] + lt2;
    float lt = vc ? (lt2.x + lt2.y) : -1e30f;
    // reduce over the 16-lane group
    lt += __shfl_xor(lt, 1, 64);
    lt += __shfl_xor(lt, 2, 64);
    lt += __shfl_xor(lt, 4, 64);
    lt += __shfl_xor(lt, 8, 64);
    float p = __expf(fminf(lt, 60.f));
    denom += p;
    f2 pv; pv.x = p; pv.y = p;
#pragma unroll
    for (int j = 0; j < 4; j++) acc2[j] = pv * v2[j] + acc2[j];
  }

  // combine the 4 edge groups (lanes ^16 / ^32 share channels)
#pragma unroll
  for (int m = 16; m <= 32; m <<= 1) {
    denom += __shfl_xor(denom, m, 64);
#pragma unroll
    for (int j = 0; j < 4; j++) {
      acc2[j].x += __shfl_xor(acc2[j].x, m, 64);
      acc2[j].y += __shfl_xor(acc2[j].y, m, 64);
    }
  }

  if (g == 0) {
    float inv = 1.f / (denom + EPS_A);
    __align__(16) bf16 ob[8];
#pragma unroll
    for (int j = 0; j < 4; j++) {
      float o0 = fmaxf(acc2[j].x * inv + par[P_BIAS2 + chb + 2*j],     0.f);
      float o1 = fmaxf(acc2[j].y * inv + par[P_BIAS2 + chb + 2*j + 1], 0.f);
      ob[2*j] = (bf16)o0; ob[2*j+1] = (bf16)o1;
    }
    *(uint4*)(h2 + (size_t)dst * F2 + chb) = *(uint4*)ob;
  }
}

// ---------------- pooling ----------------
__global__ __launch_bounds__(256) void pool_k(
    const bf16* __restrict__ h2, const int* __restrict__ gs,
    const int* __restrict__ ge, const void* __restrict__ x,
    void* __restrict__ out) {
  const int flag = detect_f32_wave(x);
  const int g = blockIdx.x;
  const int t = threadIdx.x;
  const int c = t & 127, half = t >> 7;
  int s = gs[g], e = ge[g];
  if (s < 0 || e < s) { s = 0; e = -1; }   // empty graph (memset-init) -> 0
  float sum = 0.f;
  for (int n = s + half; n <= e; n += 2)
    sum += (float)h2[(size_t)n * F2 + c];
  __shared__ float red[128];
  if (half == 1) red[c] = sum;
  __syncthreads();
  if (half == 0) {
    float tot = sum + red[c];
    float cnt = (e >= s) ? (float)(e - s + 1) : 1.f;
    float v = tot / cnt;
    if (flag) ((float*)out)[g * F2 + c] = v;
    else      ((bf16*)out)[g * F2 + c] = (bf16)v;
  }
}

// ---------------- launch ----------------
extern "C" void kernel_launch(void* const* d_in, const int* in_sizes, int n_in,
                              void* d_out, int out_size, void* d_ws, size_t ws_size,
                              hipStream_t stream) {
  (void)in_sizes; (void)n_in; (void)out_size; (void)ws_size;
  const void* x     = d_in[0];
  const int*  ei    = (const int*)d_in[1];
  const int*  batch = (const int*)d_in[2];

  char* ws = (char*)d_ws;
  float* par  = (float*)(ws + OFF_PAR);
  bf16* xl1 = (bf16*)(ws + OFF_XL1);
  bf16* xr1 = (bf16*)(ws + OFF_XR1);
  bf16* h   = (bf16*)(ws + OFF_H);
  bf16* xl2 = (bf16*)(ws + OFF_XL2);
  bf16* xr2 = (bf16*)(ws + OFF_XR2);
  bf16* h2  = (bf16*)(ws + OFF_H2);
  bf16* xb  = (bf16*)(ws + OFF_XB);
  bf16* wt1 = (bf16*)(ws + OFF_WT1);
  bf16* wt2 = (bf16*)(ws + OFF_WT2);
  int* cnt    = (int*)(ws + OFF_CNT);
  int* offs   = (int*)(ws + OFF_OFFS);
  int* cursor = (int*)(ws + OFF_CUR);
  int* csr    = (int*)(ws + OFF_CSR);
  int* gs     = (int*)(ws + OFF_GS);
  int* ge     = (int*)(ws + OFF_GE);
  int* bsum   = (int*)(ws + OFF_BS);
  int* boff   = (int*)(ws + OFF_BO);

  hipMemsetAsync(cnt, 0, (size_t)N_NODES * 4, stream);
  hipMemsetAsync(gs, 0xFF, (size_t)(OFF_WT1 - OFF_GS), stream);  // gs/ge = -1

  PrepArgs pa;
  pa.x = x; pa.ei = ei; pa.batch = batch;
  for (int i = 0; i < 12; i++) pa.src[i] = d_in[3 + i];
  const int prep_blocks = B_CVT + B_XP + B_W1 + B_W2 + B_BND + B_CNT;
  prep_k<<<prep_blocks, 256, 0, stream>>>(pa, par, xb, wt1, wt2, gs, ge, cnt);

  scan_a<<<SCAN_BLKS, 1024, 0, stream>>>(cnt, offs, bsum);
  scan_b<<<1, 64, 0, stream>>>(bsum, boff, offs);
  scan_c<<<(N_NODES + 255) / 256, 256, 0, stream>>>(boff, offs, cursor);

  gemm1_scatter_k<<<GBLK + SBL, 256, 0, stream>>>(xb, wt1, par, xl1, xr1,
                                                  ei, cursor, csr);
  agg1_k<<<(N_NODES + 3) / 4, 256, 0, stream>>>(xl1, xr1, par, offs, csr, h);
  gemm2_mfma_k<<<GBLK, 256, 0, stream>>>(h, wt2, par, xl2, xr2);
  agg2_k<<<(N_NODES + 3) / 4, 256, 0, stream>>>(xl2, xr2, par, offs, csr, h2);
  pool_k<<<NGRAPH, 256, 0, stream>>>(h2, gs, ge, x, d_out);
}

// Round 12
// 396.247 us; speedup vs baseline: 1.4987x; 1.1165x over previous
//
#include <hip/hip_runtime.h>
#include <hip/hip_bf16.h>
#include <limits.h>

// ---------------- problem constants ----------------
#define N_NODES 50000
#define N_EDGES 800000
#define TOT_E   (N_EDGES + N_NODES)   // with self loops
#define IN_F    38
#define HIDC    64
#define NH      4
#define F1      256                    // NH*HIDC
#define F2      128                    // OUT
#define NGRAPH  128
#define NEG_SLOPE 0.2f
#define EPS_A   1e-16f

typedef __hip_bfloat16 bf16;
typedef __attribute__((ext_vector_type(8))) short short8;
typedef __attribute__((ext_vector_type(16))) float f32x16;
typedef __attribute__((ext_vector_type(2))) float f2;   // lowers to VOP3P v_pk_*_f32

// ---------------- ws layout ----------------
constexpr size_t al256(size_t x) { return (x + 255) & ~(size_t)255; }

// converted-params element offsets (f32 elements) — contiguous in this order
#define P_WL1   0
#define P_BL1   (P_WL1 + IN_F * F1)        // 9728
#define P_WR1   (P_BL1 + F1)               // 9984
#define P_BR1   (P_WR1 + IN_F * F1)        // 19712
#define P_ATT1  (P_BR1 + F1)               // 19968
#define P_BIAS1 (P_ATT1 + F1)              // 20224
#define P_WL2   (P_BIAS1 + F1)             // 20480
#define P_BL2   (P_WL2 + F1 * F2)          // 53248
#define P_WR2   (P_BL2 + F2)               // 53376
#define P_BR2   (P_WR2 + F1 * F2)          // 86144
#define P_ATT2  (P_BR2 + F2)               // 86272
#define P_BIAS2 (P_ATT2 + F2)              // 86400
#define P_TOTAL (P_BIAS2 + F2)             // 86528 = 338*256 exactly

constexpr size_t OFF_PAR  = 256;
constexpr size_t OFF_XL1  = OFF_PAR + al256((size_t)P_TOTAL * 4);   // reused as h2 later
constexpr size_t OFF_XR1  = OFF_XL1 + al256((size_t)N_NODES * F1 * 2);
constexpr size_t OFF_H    = OFF_XR1 + al256((size_t)N_NODES * F1 * 2);
constexpr size_t OFF_XL2  = OFF_H   + al256((size_t)N_NODES * F1 * 2);
constexpr size_t OFF_XR2  = OFF_XL2 + al256((size_t)N_NODES * F2 * 2);
constexpr size_t OFF_CNT  = OFF_XR2 + al256((size_t)N_NODES * F2 * 2);
constexpr size_t OFF_OFFS = OFF_CNT + al256((size_t)N_NODES * 4);
constexpr size_t OFF_CSR  = OFF_OFFS+ al256((size_t)(N_NODES + 1) * 4);
constexpr size_t OFF_GS   = OFF_CSR + al256((size_t)TOT_E * 4);
constexpr size_t OFF_GE   = OFF_GS  + al256((size_t)NGRAPH * 4);    // adjacent to GS
constexpr size_t OFF_WT1  = OFF_GE  + al256((size_t)NGRAPH * 4);    // 512x64 bf16
constexpr size_t OFF_WT2  = OFF_WT1 + al256((size_t)512 * 64 * 2);  // 256x256 bf16
constexpr size_t OFF_BS   = OFF_WT2 + al256((size_t)256 * 256 * 2); // 49 block sums
constexpr size_t OFF_BO   = OFF_BS  + al256(64 * 4);                // 49 block offsets
constexpr size_t OFF_RANK = OFF_BO  + al256(64 * 4);                // per-edge rank
constexpr size_t OFF_H2   = OFF_XL1;  // xl1 dead after agg1
constexpr size_t OFF_XB   = OFF_H;    // xb (N x 64 bf16) dead before agg1 writes h

#define SCAN_BLKS 49   // ceil(50000/1024)
#define GBLK 1563      // ceil(50000/32)  gemm row-blocks
#define SBL  831       // ceil(TOT_E/1024) scatter blocks (4 edges/thread)

// ---------------- helpers ----------------
// uint4 (8 bf16) -> 4 x f2; pairs are (ch 2i, ch 2i+1)
__device__ __forceinline__ void unpack8bf2(uint4 q, f2* f) {
  unsigned v[4] = {q.x, q.y, q.z, q.w};
#pragma unroll
  for (int i = 0; i < 4; i++) {
    f2 t;
    t.x = __uint_as_float(v[i] << 16);
    t.y = __uint_as_float(v[i] & 0xffff0000u);
    f[i] = t;
  }
}

__device__ __forceinline__ void load8bf2(const bf16* __restrict__ p, f2* f) {
  unpack8bf2(*(const uint4*)p, f);
}

// leaky_relu(s) = 0.6*s + 0.4*|s|
__device__ __forceinline__ f2 lrelu2(f2 s) {
  f2 as;
  as.x = __uint_as_float(__float_as_uint(s.x) & 0x7fffffffu);
  as.y = __uint_as_float(__float_as_uint(s.y) & 0x7fffffffu);
  return 0.6f * s + 0.4f * as;
}

// wave-cooperative dtype sniff: 1 = inputs are f32, 0 = bf16.
__device__ __forceinline__ int detect_f32_wave(const void* __restrict__ x) {
  const unsigned short* u = (const unsigned short*)x;
  unsigned short b = u[threadIdx.x & 63];
  int e = (b >> 7) & 0xFF;
  unsigned long long m = __ballot(!((e == 0) || (e >= 96 && e <= 158)));
  return __popcll(m) > 8;
}

// ---------------- fused prep kernel ----------------
#define B_CVT  338
#define B_XP   12500
#define B_W1   128
#define B_W2   256
#define B_BND  196
#define B_CNT  3321

struct PrepArgs {
  const void* x;
  const void* src[12];     // Wl1,bl1,Wr1,br1,att1,bias1,Wl2,bl2,Wr2,br2,att2,bias2
  const int* ei;
  const int* batch;
};

__global__ __launch_bounds__(256) void prep_k(
    PrepArgs a, float* __restrict__ par, bf16* __restrict__ xb,
    bf16* __restrict__ wt1, bf16* __restrict__ wt2,
    int* __restrict__ gs, int* __restrict__ ge, int* __restrict__ cnt,
    int* __restrict__ rank) {
  int b = blockIdx.x;
  const int tid = threadIdx.x;

  if (b < B_CVT) {                       // ---- param convert -> f32 ----
    const int flag = detect_f32_wave(a.x);
    int idx = b * 256 + tid;             // [0, P_TOTAL)
    const void* p; int base;
    if      (idx < P_BL1)  { p = a.src[0];  base = P_WL1; }
    else if (idx < P_WR1)  { p = a.src[1];  base = P_BL1; }
    else if (idx < P_BR1)  { p = a.src[2];  base = P_WR1; }
    else if (idx < P_ATT1) { p = a.src[3];  base = P_BR1; }
    else if (idx < P_BIAS1){ p = a.src[4];  base = P_ATT1; }
    else if (idx < P_WL2)  { p = a.src[5];  base = P_BIAS1; }
    else if (idx < P_BL2)  { p = a.src[6];  base = P_WL2; }
    else if (idx < P_WR2)  { p = a.src[7];  base = P_BL2; }
    else if (idx < P_BR2)  { p = a.src[8];  base = P_WR2; }
    else if (idx < P_ATT2) { p = a.src[9];  base = P_BR2; }
    else if (idx < P_BIAS2){ p = a.src[10]; base = P_ATT2; }
    else                   { p = a.src[11]; base = P_BIAS2; }
    int li = idx - base;
    par[idx] = flag ? ((const float*)p)[li] : (float)((const bf16*)p)[li];
    return;
  }
  b -= B_CVT;
  if (b < B_XP) {                        // ---- x -> xb (N x 64, zero-pad K) ----
    const int flag = detect_f32_wave(a.x);
    int i = b * 256 + tid;               // n*64 + k
    int n = i >> 6, k = i & 63;
    float v = 0.f;
    if (k < IN_F) {
      int idx = n * IN_F + k;
      v = flag ? ((const float*)a.x)[idx] : (float)((const bf16*)a.x)[idx];
    }
    xb[i] = (bf16)v;
    return;
  }
  b -= B_XP;
  if (b < B_W1) {                        // ---- Wt1[n][k] 512x64 ----
    const int flag = detect_f32_wave(a.x);
    int i = b * 256 + tid;
    int n = i >> 6, k = i & 63;
    float v = 0.f;
    if (k < IN_F) {
      const void* W = (n < F1) ? a.src[0] : a.src[2];
      int col = (n < F1) ? n : n - F1;
      int idx = k * F1 + col;
      v = flag ? ((const float*)W)[idx] : (float)((const bf16*)W)[idx];
    }
    wt1[i] = (bf16)v;
    return;
  }
  b -= B_W1;
  if (b < B_W2) {                        // ---- Wt2[n][k] 256x256 ----
    const int flag = detect_f32_wave(a.x);
    int i = b * 256 + tid;
    int n = i >> 8, k = i & 255;
    const void* W = (n < F2) ? a.src[6] : a.src[8];
    int col = (n < F2) ? n : n - F2;
    int idx = k * F2 + col;
    float v = flag ? ((const float*)W)[idx] : (float)((const bf16*)W)[idx];
    wt2[i] = (bf16)v;
    return;
  }
  b -= B_W2;
  if (b < B_BND) {                       // ---- graph bounds (batch sorted) ----
    int n = b * 256 + tid;
    if (n >= N_NODES) return;
    int bb = a.batch[n];
    if (n == 0) gs[bb] = 0;
    else {
      int bp = a.batch[n - 1];
      if (bp != bb) { gs[bb] = n; ge[bp] = n - 1; }
    }
    if (n == N_NODES - 1) ge[bb] = N_NODES - 1;
    return;
  }
  b -= B_BND;
  {                                      // ---- degree count + per-edge rank ----
    int e = b * 256 + tid;
    if (e >= TOT_E) return;
    int dst = (e < N_EDGES) ? a.ei[N_EDGES + e] : (e - N_EDGES);
    rank[e] = atomicAdd(&cnt[dst], 1);   // rank within dst (order-free)
  }
}

// ---------------- fused: GEMM1 (MFMA 32x32x16) || atomic-free scatter ----------------
// blocks [0,GBLK): xb(N,64) @ Wt1^T -> xl1|xr1. blocks [GBLK,GBLK+SBL): CSR
// scatter via precomputed rank: csr[offs[dst]+rank[e]] = src. No atomics, no
// dependent chain — pure fire-and-forget stores.
__global__ __launch_bounds__(256) void gemm1_scatter_k(
    const bf16* __restrict__ xb, const bf16* __restrict__ wt1,
    const float* __restrict__ par,
    bf16* __restrict__ xl1, bf16* __restrict__ xr1,
    const int* __restrict__ ei, const int* __restrict__ offs,
    const int* __restrict__ rank, int* __restrict__ csr) {
  if (blockIdx.x >= GBLK) {              // ---- scatter path ----
    int base = (blockIdx.x - GBLK) * 1024 + threadIdx.x;
#pragma unroll
    for (int i = 0; i < 4; i++) {
      int e = base + i * 256;
      if (e >= TOT_E) continue;
      int src, dst;
      if (e < N_EDGES) { src = ei[e]; dst = ei[N_EDGES + e]; }
      else             { src = dst = e - N_EDGES; }
      csr[offs[dst] + rank[e]] = src;
    }
    return;
  }
  // ---- gemm1 path: 32x32x16 MFMA. Wave w: rows blk*32..+31, cols w*128..+127 ----
  const int w = threadIdx.x >> 6, lane = threadIdx.x & 63;
  const int m0 = blockIdx.x * 32;
  const int colbase = w * 128;
  const int lm = lane & 31;       // m / n index
  const int kh = lane >> 5;       // k-half (8 of 16)

  int arow = m0 + lm; if (arow >= N_NODES) arow = N_NODES - 1;
  short8 afr[4];
#pragma unroll
  for (int kk = 0; kk < 4; kk++)
    afr[kk] = *(const short8*)(xb + (size_t)arow * 64 + kk * 16 + kh * 8);

  f32x16 acc[4] = {};
#pragma unroll
  for (int t = 0; t < 4; t++) {
    int n = colbase + t * 32 + lm;
#pragma unroll
    for (int kk = 0; kk < 4; kk++) {
      short8 b = *(const short8*)(wt1 + (size_t)n * 64 + kk * 16 + kh * 8);
      acc[t] = __builtin_amdgcn_mfma_f32_32x32x16_bf16(afr[kk], b, acc[t], 0, 0, 0);
    }
  }

  // C/D: col = lane&31 (+tile), row = (reg&3) + 8*(reg>>2) + 4*kh  [m74/m101]
#pragma unroll
  for (int t = 0; t < 4; t++) {
    int col = colbase + t * 32 + lm;
    bf16* dst = (col < F1) ? xl1 : xr1;
    int c = (col < F1) ? col : col - F1;
    float bv = (col < F1) ? par[P_BL1 + c] : par[P_BR1 + c];
#pragma unroll
    for (int reg = 0; reg < 16; reg++) {
      int row = m0 + (reg & 3) + 8 * (reg >> 2) + 4 * kh;
      if (row < N_NODES)
        dst[(size_t)row * F1 + c] = (bf16)(acc[t][reg] + bv);
    }
  }
}

// ---------------- GEMM 2 (MFMA 32x32x16): h(N,256) @ Wt2^T -> xl2|xr2 ----------------
__global__ __launch_bounds__(256) void gemm2_mfma_k(
    const bf16* __restrict__ h, const bf16* __restrict__ wt2,
    const float* __restrict__ par,
    bf16* __restrict__ xl2, bf16* __restrict__ xr2) {
  const int w = threadIdx.x >> 6, lane = threadIdx.x & 63;
  const int m0 = blockIdx.x * 32;
  const int colbase = w * 64;
  const int lm = lane & 31;
  const int kh = lane >> 5;

  int arow = m0 + lm; if (arow >= N_NODES) arow = N_NODES - 1;
  const bf16* hrow = h + (size_t)arow * F1 + kh * 8;

  f32x16 acc[2] = {};
#pragma unroll
  for (int kk = 0; kk < 16; kk++) {
    short8 a = *(const short8*)(hrow + kk * 16);
#pragma unroll
    for (int t = 0; t < 2; t++) {
      int n = colbase + t * 32 + lm;
      short8 b = *(const short8*)(wt2 + (size_t)n * 256 + kk * 16 + kh * 8);
      acc[t] = __builtin_amdgcn_mfma_f32_32x32x16_bf16(a, b, acc[t], 0, 0, 0);
    }
  }

#pragma unroll
  for (int t = 0; t < 2; t++) {
    int col = colbase + t * 32 + lm;
    bf16* dst = (col < F2) ? xl2 : xr2;
    int c = (col < F2) ? col : col - F2;
    float bv = (col < F2) ? par[P_BL2 + c] : par[P_BR2 + c];
#pragma unroll
    for (int reg = 0; reg < 16; reg++) {
      int row = m0 + (reg & 3) + 8 * (reg >> 2) + 4 * kh;
      if (row < N_NODES)
        dst[(size_t)row * F2 + c] = (bf16)(acc[t][reg] + bv);
    }
  }
}

// ---------------- CSR scan (3-phase, multi-block) ----------------
__global__ __launch_bounds__(1024) void scan_a(const int* __restrict__ cnt,
                                               int* __restrict__ offs,
                                               int* __restrict__ bsum) {
  __shared__ int wsum[16];
  const int t = threadIdx.x;
  const int lane = t & 63, w = t >> 6;
  int idx = blockIdx.x * 1024 + t;
  int v = (idx < N_NODES) ? cnt[idx] : 0;
  int s = v;
#pragma unroll
  for (int off = 1; off < 64; off <<= 1) {
    int u = __shfl_up(s, off, 64);
    if (lane >= off) s += u;
  }
  if (lane == 63) wsum[w] = s;
  __syncthreads();
  int prefix = 0;
  for (int i = 0; i < w; i++) prefix += wsum[i];
  if (idx < N_NODES) offs[idx] = prefix + s - v;   // exclusive within block
  if (t == 1023) bsum[blockIdx.x] = prefix + s;    // block total
}

__global__ void scan_b(const int* __restrict__ bsum, int* __restrict__ boff,
                       int* __restrict__ offs) {
  const int lane = threadIdx.x;   // 64 threads, SCAN_BLKS<=64 values
  int v = (lane < SCAN_BLKS) ? bsum[lane] : 0;
  int s = v;
#pragma unroll
  for (int off = 1; off < 64; off <<= 1) {
    int u = __shfl_up(s, off, 64);
    if (lane >= off) s += u;
  }
  if (lane < SCAN_BLKS) boff[lane] = s - v;
  if (lane == SCAN_BLKS - 1) offs[N_NODES] = s;   // grand total
}

__global__ void scan_c(const int* __restrict__ boff, int* __restrict__ offs) {
  int idx = blockIdx.x * 256 + threadIdx.x;
  if (idx >= N_NODES) return;
  offs[idx] = offs[idx] + boff[idx >> 10];
}

// ---------------- layer-1 aggregation: one wave per dst, 2 groups x 32 lanes,
// register double-buffer prefetch of the next edge's row ----------------
__global__ __launch_bounds__(256, 4) void agg1_k(
    const bf16* __restrict__ xl1, const bf16* __restrict__ xr1,
    const float* __restrict__ par,
    const int* __restrict__ offs, const int* __restrict__ csr,
    bf16* __restrict__ hout) {
  const int dst = blockIdx.x * 4 + (threadIdx.x >> 6);
  if (dst >= N_NODES) return;
  const int lane = threadIdx.x & 63;
  const int g = lane >> 5;        // 2 edge groups
  const int sl = lane & 31;
  const int chb = sl * 8;

  f2 r2[4], a2[4];
  load8bf2(xr1 + (size_t)dst * F1 + chb, r2);
  {
    float4 aa = *(const float4*)(par + P_ATT1 + chb);
    float4 ab = *(const float4*)(par + P_ATT1 + chb + 4);
    a2[0].x = aa.x; a2[0].y = aa.y; a2[1].x = aa.z; a2[1].y = aa.w;
    a2[2].x = ab.x; a2[2].y = ab.y; a2[3].x = ab.z; a2[3].y = ab.w;
  }

  const int e0 = offs[dst], e1 = offs[dst + 1];
  const f2 zf2 = {0.f, 0.f};
  f2 acc2[4];
#pragma unroll
  for (int j = 0; j < 4; j++) acc2[j] = zf2;
  float denom = 0.f;

  // prime the pipeline: edge e0+g
  int e = e0 + g;
  const uint4 zq = {0, 0, 0, 0};
  bool valid = e < e1;
  uint4 q = valid ? *(const uint4*)(xl1 + (size_t)csr[e] * F1 + chb) : zq;

  for (int base = e0; base < e1; base += 2) {
    const uint4 qc = q;
    const bool vc = valid;
    // prefetch next edge's row before touching qc
    e += 2;
    valid = e < e1;
    q = valid ? *(const uint4*)(xl1 + (size_t)csr[e] * F1 + chb) : zq;

    f2 v2[4];
    unpack8bf2(qc, v2);     // invalid -> zeros
    f2 lt2 = zf2;
#pragma unroll
    for (int j = 0; j < 4; j++)
      lt2 = lrelu2(v2[j] + r2[j]) * a2[j] + lt2;
    float lt = vc ? (lt2.x + lt2.y) : -1e30f;
    // per-head reduce over this lane's 8-lane head subgroup
    lt += __shfl_xor(lt, 1, 64);
    lt += __shfl_xor(lt, 2, 64);
    lt += __shfl_xor(lt, 4, 64);
    float p = __expf(fminf(lt, 60.f));   // logits O(1); invalid group -> 0
    denom += p;
    f2 pv; pv.x = p; pv.y = p;
#pragma unroll
    for (int j = 0; j < 4; j++) acc2[j] = pv * v2[j] + acc2[j];
  }

  // combine the 2 edge groups (lane ^ 32 has same channels & head)
  denom += __shfl_xor(denom, 32, 64);
#pragma unroll
  for (int j = 0; j < 4; j++) {
    acc2[j].x += __shfl_xor(acc2[j].x, 32, 64);
    acc2[j].y += __shfl_xor(acc2[j].y, 32, 64);
  }

  if (g == 0) {
    float inv = 1.f / (denom + EPS_A);
    __align__(16) bf16 ob[8];
#pragma unroll
    for (int j = 0; j < 4; j++) {
      float o0 = fmaxf(acc2[j].x * inv + par[P_BIAS1 + chb + 2*j],     0.f);
      float o1 = fmaxf(acc2[j].y * inv + par[P_BIAS1 + chb + 2*j + 1], 0.f);
      ob[2*j] = (bf16)o0; ob[2*j+1] = (bf16)o1;
    }
    *(uint4*)(hout + (size_t)dst * F1 + chb) = *(uint4*)ob;
  }
}

// ---------------- layer-2 aggregation: one wave per dst, 4 groups x 16 lanes,
// 8 ch/lane (single 16B load) + register prefetch ----------------
__global__ __launch_bounds__(256, 4) void agg2_k(
    const bf16* __restrict__ xl2, const bf16* __restrict__ xr2,
    const float* __restrict__ par,
    const int* __restrict__ offs, const int* __restrict__ csr,
    bf16* __restrict__ h2) {
  const int dst = blockIdx.x * 4 + (threadIdx.x >> 6);
  if (dst >= N_NODES) return;
  const int lane = threadIdx.x & 63;
  const int g = lane >> 4;        // 4 edge groups
  const int sl = lane & 15;
  const int chb = sl * 8;

  f2 r2[4], a2[4];
  load8bf2(xr2 + (size_t)dst * F2 + chb, r2);
  {
    float4 aa = *(const float4*)(par + P_ATT2 + chb);
    float4 ab = *(const float4*)(par + P_ATT2 + chb + 4);
    a2[0].x = aa.x; a2[0].y = aa.y; a2[1].x = aa.z; a2[1].y = aa.w;
    a2[2].x = ab.x; a2[2].y = ab.y; a2[3].x = ab.z; a2[3].y = ab.w;
  }

  const int e0 = offs[dst], e1 = offs[dst + 1];
  const f2 zf2 = {0.f, 0.f};
  f2 acc2[4];
#pragma unroll
  for (int j = 0; j < 4; j++) acc2[j] = zf2;
  float denom = 0.f;

  const uint4 zq = {0, 0, 0, 0};
  int e = e0 + g;
  bool valid = e < e1;
  uint4 q = valid ? *(const uint4*)(xl2 + (size_t)csr[e] * F2 + chb) : zq;

  for (int base = e0; base < e1; base += 4) {
    const uint4 qc = q;
    const bool vc = valid;
    e += 4;
    valid = e < e1;
    q = valid ? *(const uint4*)(xl2 + (size_t)csr[e] * F2 + chb) : zq;

    f2 v2[4];
    unpack8bf2(qc, v2);
    f2 lt2 = zf2;
#pragma unroll
    for (int j = 0; j < 4; j++)
      lt2 = lrelu2(v2[j] + r2[j]) * a2[j] + lt2;
    float lt = vc ? (lt2.x + lt2.y) : -1e30f;
    // reduce over the 16-lane group
    lt += __shfl_xor(lt, 1, 64);
    lt += __shfl_xor(lt, 2, 64);
    lt += __shfl_xor(lt, 4, 64);
    lt += __shfl_xor(lt, 8, 64);
    float p = __expf(fminf(lt, 60.f));
    denom += p;
    f2 pv; pv.x = p; pv.y = p;
#pragma unroll
    for (int j = 0; j < 4; j++) acc2[j] = pv * v2[j] + acc2[j];
  }

  // combine the 4 edge groups (lanes ^16 / ^32 share channels)
#pragma unroll
  for (int m = 16; m <= 32; m <<= 1) {
    denom += __shfl_xor(denom, m, 64);
#pragma unroll
    for (int j = 0; j < 4; j++) {
      acc2[j].x += __shfl_xor(acc2[j].x, m, 64);
      acc2[j].y += __shfl_xor(acc2[j].y, m, 64);
    }
  }

  if (g == 0) {
    float inv = 1.f / (denom + EPS_A);
    __align__(16) bf16 ob[8];
#pragma unroll
    for (int j = 0; j < 4; j++) {
      float o0 = fmaxf(acc2[j].x * inv + par[P_BIAS2 + chb + 2*j],     0.f);
      float o1 = fmaxf(acc2[j].y * inv + par[P_BIAS2 + chb + 2*j + 1], 0.f);
      ob[2*j] = (bf16)o0; ob[2*j+1] = (bf16)o1;
    }
    *(uint4*)(h2 + (size_t)dst * F2 + chb) = *(uint4*)ob;
  }
}

// ---------------- pooling ----------------
__global__ __launch_bounds__(256) void pool_k(
    const bf16* __restrict__ h2, const int* __restrict__ gs,
    const int* __restrict__ ge, const void* __restrict__ x,
    void* __restrict__ out) {
  const int flag = detect_f32_wave(x);
  const int g = blockIdx.x;
  const int t = threadIdx.x;
  const int c = t & 127, half = t >> 7;
  int s = gs[g], e = ge[g];
  if (s < 0 || e < s) { s = 0; e = -1; }   // empty graph (memset-init) -> 0
  float sum = 0.f;
  for (int n = s + half; n <= e; n += 2)
    sum += (float)h2[(size_t)n * F2 + c];
  __shared__ float red[128];
  if (half == 1) red[c] = sum;
  __syncthreads();
  if (half == 0) {
    float tot = sum + red[c];
    float cnt = (e >= s) ? (float)(e - s + 1) : 1.f;
    float v = tot / cnt;
    if (flag) ((float*)out)[g * F2 + c] = v;
    else      ((bf16*)out)[g * F2 + c] = (bf16)v;
  }
}

// ---------------- launch ----------------
extern "C" void kernel_launch(void* const* d_in, const int* in_sizes, int n_in,
                              void* d_out, int out_size, void* d_ws, size_t ws_size,
                              hipStream_t stream) {
  (void)in_sizes; (void)n_in; (void)out_size; (void)ws_size;
  const void* x     = d_in[0];
  const int*  ei    = (const int*)d_in[1];
  const int*  batch = (const int*)d_in[2];

  char* ws = (char*)d_ws;
  float* par  = (float*)(ws + OFF_PAR);
  bf16* xl1 = (bf16*)(ws + OFF_XL1);
  bf16* xr1 = (bf16*)(ws + OFF_XR1);
  bf16* h   = (bf16*)(ws + OFF_H);
  bf16* xl2 = (bf16*)(ws + OFF_XL2);
  bf16* xr2 = (bf16*)(ws + OFF_XR2);
  bf16* h2  = (bf16*)(ws + OFF_H2);
  bf16* xb  = (bf16*)(ws + OFF_XB);
  bf16* wt1 = (bf16*)(ws + OFF_WT1);
  bf16* wt2 = (bf16*)(ws + OFF_WT2);
  int* cnt    = (int*)(ws + OFF_CNT);
  int* offs   = (int*)(ws + OFF_OFFS);
  int* csr    = (int*)(ws + OFF_CSR);
  int* gs     = (int*)(ws + OFF_GS);
  int* ge     = (int*)(ws + OFF_GE);
  int* bsum   = (int*)(ws + OFF_BS);
  int* boff   = (int*)(ws + OFF_BO);
  int* rank   = (int*)(ws + OFF_RANK);

  hipMemsetAsync(cnt, 0, (size_t)N_NODES * 4, stream);
  hipMemsetAsync(gs, 0xFF, (size_t)(OFF_WT1 - OFF_GS), stream);  // gs/ge = -1

  PrepArgs pa;
  pa.x = x; pa.ei = ei; pa.batch = batch;
  for (int i = 0; i < 12; i++) pa.src[i] = d_in[3 + i];
  const int prep_blocks = B_CVT + B_XP + B_W1 + B_W2 + B_BND + B_CNT;
  prep_k<<<prep_blocks, 256, 0, stream>>>(pa, par, xb, wt1, wt2, gs, ge, cnt, rank);

  scan_a<<<SCAN_BLKS, 1024, 0, stream>>>(cnt, offs, bsum);
  scan_b<<<1, 64, 0, stream>>>(bsum, boff, offs);
  scan_c<<<(N_NODES + 255) / 256, 256, 0, stream>>>(boff, offs);

  gemm1_scatter_k<<<GBLK + SBL, 256, 0, stream>>>(xb, wt1, par, xl1, xr1,
                                                  ei, offs, rank, csr);
  agg1_k<<<(N_NODES + 3) / 4, 256, 0, stream>>>(xl1, xr1, par, offs, csr, h);
  gemm2_mfma_k<<<GBLK, 256, 0, stream>>>(h, wt2, par, xl2, xr2);
  agg2_k<<<(N_NODES + 3) / 4, 256, 0, stream>>>(xl2, xr2, par, offs, csr, h2);
  pool_k<<<NGRAPH, 256, 0, stream>>>(h2, gs, ge, x, d_out);
}